// Round 1
// baseline (1390.563 us; speedup 1.0000x reference)
//
#include <hip/hip_runtime.h>
#include <cfloat>

#define B_  8
#define N_  2048
#define H_  256
#define L_  4
#define K_  16
#define G_  512
#define M0_ 256
#define M1_ 128
#define C_  128
#define BN_ 16384   // B_*N_
#define KP_ 768     // packed split-bf16 K (3*H_)

typedef unsigned short ushort_t;
typedef __attribute__((ext_vector_type(8))) short short8;
typedef __attribute__((ext_vector_type(4))) float f32x4;

// ---------------- workspace layout (bytes) ----------------
#define OFF_H     ((size_t)0)            // 16 MB  h (fp32, persistent)
#define OFF_APACK ((size_t)16777216)     // 25.2 MB  P-pack [hi,lo,hi] (Q read via seg remap)
#define OFF_SQ    ((size_t)67108864)     // 64 KB
#define OFF_IDX   ((size_t)67174400)     // 1 MB
#define OFF_STATS ((size_t)68222976)     // 4 KB (512 doubles)
#define OFF_SCSH  ((size_t)68227072)     // 2 KB
#define OFF_BCAT  ((size_t)68229120)     // 2 KB
#define OFF_P0    ((size_t)68231168)     // 16 KB
#define OFF_P1    ((size_t)68247552)
#define OFF_P2    ((size_t)68255744)
#define OFF_D     ((size_t)69206016)     // former dmat region; overlays below (stream-ordered safe)
// top-16 candidate arrays (replace dmat): keys 33.55 MB + cols 16.78 MB = exactly the 50.33 MB gap
#define OFF_CK    (OFF_D)                              // kcand u32 [16384][32][16]
#define OFF_CC    (OFF_D + (size_t)33554432)           // ccand u16 [16384][32][16]
#define OFF_T     (OFF_D + (size_t)0)           // 16 MB (alive gather_max -> bn2; cand dead)
#define OFF_UV    (OFF_D + (size_t)50331648)    // 33.5 MB (alive uv gemm -> gather); also y
#define OFF_QW    (OFF_D + (size_t)83886080)    // 0.79 MB weight packs
#define OFF_PMAX  (OFF_D + (size_t)84672512)    // 256 KB
#define WS_NEEDED ((size_t)203423744)

// ---------------- helpers ----------------
static __device__ __forceinline__ ushort_t f2bf(float f) {
    unsigned u = __float_as_uint(f);
    unsigned r = (u + 0x7fffu + ((u >> 16) & 1u)) >> 16;   // RNE
    return (ushort_t)r;
}
static __device__ __forceinline__ float bf2f(ushort_t h) {
    return __uint_as_float(((unsigned)h) << 16);
}
// monotone f32 -> u32 sortkey (same transform as original topk16)
static __device__ __forceinline__ unsigned f2key(float f) {
    unsigned u = __float_as_uint(f);
    return (u & 0x80000000u) ? ~u : (u | 0x80000000u);
}
// P-pack layout per row: [hi(0:256), lo(256:512), hi(512:768)]
static __device__ __forceinline__ void pack3(float v, ushort_t* A, size_t base, int f) {
    ushort_t hi = f2bf(v);
    ushort_t lo = f2bf(v - bf2f(hi));
    A[base + f] = hi; A[base + H_ + f] = lo; A[base + 2 * H_ + f] = hi;
}

// ---- in-lane sorting primitives (all static indices -> registers) ----
#define CEA(x, y) { unsigned mn_ = min(x, y), mx_ = max(x, y); (x) = mn_; (y) = mx_; }

static __device__ __forceinline__ void sortnet16(unsigned* s) {
#pragma unroll
    for (int k = 2; k <= 16; k <<= 1) {
#pragma unroll
        for (int j = k >> 1; j > 0; j >>= 1) {
#pragma unroll
            for (int i = 0; i < 16; ++i) {
                int l = i ^ j;
                if (l > i) {
                    if ((i & k) == 0) { CEA(s[i], s[l]); }
                    else              { CEA(s[l], s[i]); }
                }
            }
        }
    }
}
// bitonic input -> sorted ascending
static __device__ __forceinline__ void clean16(unsigned* s) {
#pragma unroll
    for (int j = 8; j > 0; j >>= 1) {
#pragma unroll
        for (int i = 0; i < 16; ++i) {
            int l = i ^ j;
            if (l > i) { CEA(s[i], s[l]); }
        }
    }
}

// one lane owns one 64-value row in arena (stride 66 u32); emit exact 16 smallest
// by (key, col) lex order as 16 u32 keys + 16 u16 cols.
static __device__ __forceinline__ void select_emit(
    unsigned* arena_wave, int lane,
    unsigned* __restrict__ kc, ushort_t* __restrict__ cc,
    size_t Rrow, int chunk) {
    unsigned* mr = arena_wave + lane * 66;
    unsigned v[64];
#pragma unroll
    for (int i = 0; i < 32; ++i) {
        uint2 t2 = *(const uint2*)(mr + 2 * i);
        v[2 * i] = t2.x; v[2 * i + 1] = t2.y;
    }
    // exact 16th-smallest key T: sort 4 groups of 16, bitonic low-merge tree
    unsigned a[16], b[16], m1[16], m2[16];
#pragma unroll
    for (int i = 0; i < 16; ++i) { a[i] = v[i]; b[i] = v[16 + i]; }
    sortnet16(a); sortnet16(b);
#pragma unroll
    for (int i = 0; i < 16; ++i) m1[i] = min(a[i], b[15 - i]);
    clean16(m1);
#pragma unroll
    for (int i = 0; i < 16; ++i) { a[i] = v[32 + i]; b[i] = v[48 + i]; }
    sortnet16(a); sortnet16(b);
#pragma unroll
    for (int i = 0; i < 16; ++i) m2[i] = min(a[i], b[15 - i]);
    clean16(m2);
    unsigned T = 0;
#pragma unroll
    for (int i = 0; i < 16; ++i) T = max(T, min(m1[i], m2[15 - i]));
    // phase 2: exact top-16 set = all {key < T} + ties at T by ascending col.
    // #{<T} <= 15 and #{<=T} >= 16 by definition of T, so cnt ends at 16.
    int cnt = 0;
#pragma unroll
    for (int i = 0; i < 64; ++i) {
        if (v[i] < T) { mr[cnt] = v[i]; mr[16 + cnt] = (unsigned)i; ++cnt; }
    }
#pragma unroll
    for (int i = 0; i < 64; ++i) {
        if (v[i] == T && cnt < 16) { mr[cnt] = v[i]; mr[16 + cnt] = (unsigned)i; ++cnt; }
    }
    // readback + packed emit (plain stores: 50 MB -> L3-resident for merge kernel)
    unsigned kk[16], c16[16];
#pragma unroll
    for (int i = 0; i < 8; ++i) {
        uint2 tk = *(const uint2*)(mr + 2 * i);
        kk[2 * i] = tk.x; kk[2 * i + 1] = tk.y;
        uint2 tc = *(const uint2*)(mr + 16 + 2 * i);
        c16[2 * i] = tc.x; c16[2 * i + 1] = tc.y;
    }
    size_t kb = (Rrow * 32 + (size_t)chunk) * 16;
    *(uint4*)(kc + kb)      = make_uint4(kk[0],  kk[1],  kk[2],  kk[3]);
    *(uint4*)(kc + kb + 4)  = make_uint4(kk[4],  kk[5],  kk[6],  kk[7]);
    *(uint4*)(kc + kb + 8)  = make_uint4(kk[8],  kk[9],  kk[10], kk[11]);
    *(uint4*)(kc + kb + 12) = make_uint4(kk[12], kk[13], kk[14], kk[15]);
    unsigned w[8];
#pragma unroll
    for (int i = 0; i < 8; ++i) w[i] = c16[2 * i] | (c16[2 * i + 1] << 16);
    *(uint4*)(cc + kb)     = make_uint4(w[0], w[1], w[2], w[3]);
    *(uint4*)(cc + kb + 8) = make_uint4(w[4], w[5], w[6], w[7]);
}

// ---------------- kernels ----------------

// h = x @ Wf + bf ; also pack h into Apack
__global__ void feat_pack(const float* __restrict__ x, const float* __restrict__ Wf,
                          const float* __restrict__ bfv, float* __restrict__ h,
                          ushort_t* __restrict__ Ap) {
    int pt = blockIdx.x;
    int f  = threadIdx.x;
    float x0 = x[pt * 3 + 0], x1 = x[pt * 3 + 1], x2 = x[pt * 3 + 2];
    float v = x0 * Wf[f] + x1 * Wf[H_ + f] + x2 * Wf[2 * H_ + f] + bfv[f];
    h[(size_t)pt * H_ + f] = v;
    pack3(v, Ap, (size_t)pt * KP_, f);
}

// W (256 x Nd) -> Qpack (Nd x 768) rows [hi,hi,lo] of W^T
__global__ void pack_wT(const float* __restrict__ W, ushort_t* __restrict__ Qp, int Nd) {
    int n = blockIdx.x, k = threadIdx.x;
    float w = W[(size_t)k * Nd + n];
    ushort_t hi = f2bf(w), lo = f2bf(w - bf2f(hi));
    size_t base = (size_t)n * KP_;
    Qp[base + k] = hi; Qp[base + H_ + k] = hi; Qp[base + 2 * H_ + k] = lo;
}

// Qcat for fused u|v gemm: rows 0..255 = (We_a - We_b)^T, rows 256..511 = We_b^T
__global__ void pack_qcat(const float* __restrict__ We_l, const float* __restrict__ be_l,
                          ushort_t* __restrict__ Qp, float* __restrict__ bcat) {
    int n = blockIdx.x, k = threadIdx.x;
    float w;
    if (n < H_) w = We_l[(size_t)k * H_ + n] - We_l[(size_t)H_ * H_ + (size_t)k * H_ + n];
    else        w = We_l[(size_t)H_ * H_ + (size_t)k * H_ + (n - H_)];
    ushort_t hi = f2bf(w), lo = f2bf(w - bf2f(hi));
    size_t base = (size_t)n * KP_;
    Qp[base + k] = hi; Qp[base + H_ + k] = hi; Qp[base + 2 * H_ + k] = lo;
    if (k == 0) bcat[n] = (n < H_) ? be_l[n] : 0.f;
}

// ---- split-bf16 MFMA GEMM: out = P (M x K) . Q^T (N x K) ----
// mode 0: out[r][c] = acc + aux[c]
// mode 2: out[r][c] = resid[r][c] + alphap[aidx]*(acc+aux[c])
// stats != nullptr: accumulate per-column sum/sumsq of written values (BN prestats)
// nx != 0: 1-D grid of nx*128 blocks, XCD-pinned: z=blk&7 owns M-rows of batch z.
__global__ __launch_bounds__(256) void mfma_gemm(
    const ushort_t* __restrict__ P, const ushort_t* __restrict__ Q,
    const float* __restrict__ aux, float* __restrict__ out,
    int Kd, int ldOut, int mode, const float* __restrict__ resid,
    const float* __restrict__ alphap, int aidx, double* __restrict__ stats,
    int nx) {
    __shared__ __align__(16) ushort_t As[128 * 32];
    __shared__ __align__(16) ushort_t Bs[128 * 32];
    __shared__ float cs1[4][64], cs2[4][64];
    int i0, j0;
    if (nx) {
        int blk = blockIdx.x;
        int z = blk & 7;
        int rest = blk >> 3;
        int xb = rest % nx;
        int ys = rest / nx;            // 0..15
        i0 = (z * 16 + ys) * 128;
        j0 = xb * 128;
    } else {
        i0 = blockIdx.y * 128; j0 = blockIdx.x * 128;
    }
    int tid = threadIdx.x;
    int lane = tid & 63, wave = tid >> 6;
    int wm = wave & 1, wn = wave >> 1;
    int m16 = lane & 15, kq = (lane >> 4) * 8;

    f32x4 acc[4][4];
    f32x4 zero = {0.f, 0.f, 0.f, 0.f};
#pragma unroll
    for (int i = 0; i < 4; ++i)
#pragma unroll
        for (int j = 0; j < 4; ++j) acc[i][j] = zero;

    int srow = tid >> 2;
    int skc  = (tid & 3) * 8;

    for (int k0 = 0; k0 < Kd; k0 += 32) {
#pragma unroll
        for (int s = 0; s < 2; ++s) {
            int row = srow + s * 64;
            const ushort_t* gpA = P + (size_t)(i0 + row) * Kd + k0 + skc;
            const ushort_t* gpB = Q + (size_t)(j0 + row) * Kd + k0 + skc;
            __builtin_amdgcn_global_load_lds(
                (const __attribute__((address_space(1))) void*)gpA,
                (__attribute__((address_space(3))) void*)(As + (size_t)(wave * 64 + s * 256) * 8),
                16, 0, 0);
            __builtin_amdgcn_global_load_lds(
                (const __attribute__((address_space(1))) void*)gpB,
                (__attribute__((address_space(3))) void*)(Bs + (size_t)(wave * 64 + s * 256) * 8),
                16, 0, 0);
        }
        __syncthreads();
        short8 af[4], bfr[4];
#pragma unroll
        for (int fi = 0; fi < 4; ++fi)
            af[fi] = *(const short8*)(As + (wm * 64 + fi * 16 + m16) * 32 + kq);
#pragma unroll
        for (int fj = 0; fj < 4; ++fj)
            bfr[fj] = *(const short8*)(Bs + (wn * 64 + fj * 16 + m16) * 32 + kq);
#pragma unroll
        for (int fi = 0; fi < 4; ++fi)
#pragma unroll
            for (int fj = 0; fj < 4; ++fj)
                acc[fi][fj] = __builtin_amdgcn_mfma_f32_16x16x32_bf16(
                    af[fi], bfr[fj], acc[fi][fj], 0, 0, 0);
        __syncthreads();
    }
    float alpha = (mode == 2) ? alphap[aidx] : 0.f;
    int rbase = i0 + wm * 64 + (lane >> 4) * 4;
    int cbase = j0 + wn * 64 + m16;
    float s1[4] = {0.f, 0.f, 0.f, 0.f}, s2[4] = {0.f, 0.f, 0.f, 0.f};
#pragma unroll
    for (int fi = 0; fi < 4; ++fi) {
#pragma unroll
        for (int fj = 0; fj < 4; ++fj) {
            int c = cbase + fj * 16;
            float a = aux[c];
#pragma unroll
            for (int r = 0; r < 4; ++r) {
                int gr = rbase + fi * 16 + r;
                size_t oidx = (size_t)gr * ldOut + c;
                float val;
                if (mode == 2) val = resid[oidx] + alpha * (acc[fi][fj][r] + a);
                else           val = acc[fi][fj][r] + a;
                out[oidx] = val;
                s1[fj] += val; s2[fj] += val * val;
            }
        }
    }
    if (stats) {
#pragma unroll
        for (int fj = 0; fj < 4; ++fj) {
            float a1 = s1[fj], a2 = s2[fj];
            a1 += __shfl_xor(a1, 16); a1 += __shfl_xor(a1, 32);
            a2 += __shfl_xor(a2, 16); a2 += __shfl_xor(a2, 32);
            if ((lane >> 4) == 0) {
                cs1[wave][fj * 16 + m16] = a1;
                cs2[wave][fj * 16 + m16] = a2;
            }
        }
        __syncthreads();
        if (tid < 128) {
            int wnl = tid >> 6, cl = tid & 63;
            float t1 = cs1[2 * wnl][cl] + cs1[2 * wnl + 1][cl];
            float t2 = cs2[2 * wnl][cl] + cs2[2 * wnl + 1][cl];
            int c = j0 + tid;
            atomicAdd(&stats[c], (double)t1);
            atomicAdd(&stats[H_ + c], (double)t2);
        }
    }
}

// ---- symmetric gram + fused per-chunk top-16 candidate emission ----
// D values (sq[j] - 2<xi,xj>) are never materialized. Each wave transposes its
// 64x64 acc tile (as u32 sortkeys) into a private LDS arena [64][66]; each lane
// then owns one full 64-value row-chunk and emits the exact 16 smallest by
// (value, col) lex order: 16 u32 keys + 16 u16 cols per (row, 64-col chunk).
// Union over a row's 32 chunks provably contains the row's global top-16.
// Dynamic LDS: 4 waves * 64*66 u32 = 67,584 B (As/Bs aliased, dead post-loop).
__global__ __launch_bounds__(256) void gram_sym(const ushort_t* __restrict__ Ap,
                                                const float* __restrict__ sqb,
                                                unsigned* __restrict__ kc,
                                                ushort_t* __restrict__ cc) {
    extern __shared__ __align__(16) unsigned dyns[];
    ushort_t* As = (ushort_t*)dyns;          // 8 KB (k-loop only)
    ushort_t* Bs = (ushort_t*)dyns + 4096;   // 8 KB (k-loop only)
    int blk = blockIdx.x;
    int z = blk & 7;
    int p = blk >> 3;
    int bi = 0, rem = p;
    while (rem >= 16 - bi) { rem -= 16 - bi; ++bi; }
    int bj = bi + rem;
    const ushort_t* Pz = Ap + (size_t)z * N_ * KP_;
    const float* sqz = sqb + (size_t)z * N_;
    int i0 = bi * 128, j0 = bj * 128;

    int tid = threadIdx.x;
    int lane = tid & 63, wave = tid >> 6;
    int wm = wave & 1, wn = wave >> 1;
    int m16 = lane & 15, q4 = lane >> 4;
    int kq = q4 * 8;

    f32x4 acc[4][4];
    f32x4 zero = {0.f, 0.f, 0.f, 0.f};
#pragma unroll
    for (int i = 0; i < 4; ++i)
#pragma unroll
        for (int j = 0; j < 4; ++j) acc[i][j] = zero;

    int srow = tid >> 2;
    int skc  = (tid & 3) * 8;

    for (int k0 = 0; k0 < KP_; k0 += 32) {
        // Q segment remap: seg0->seg0(hi), seg1->seg2(hi), seg2->seg1(lo)
        int kb = (k0 < 256) ? k0 : ((k0 < 512) ? k0 + 256 : k0 - 256);
#pragma unroll
        for (int s = 0; s < 2; ++s) {
            int row = srow + s * 64;
            const ushort_t* gpA = Pz + (size_t)(i0 + row) * KP_ + k0 + skc;
            const ushort_t* gpB = Pz + (size_t)(j0 + row) * KP_ + kb + skc;
            __builtin_amdgcn_global_load_lds(
                (const __attribute__((address_space(1))) void*)gpA,
                (__attribute__((address_space(3))) void*)(As + (size_t)(wave * 64 + s * 256) * 8),
                16, 0, 0);
            __builtin_amdgcn_global_load_lds(
                (const __attribute__((address_space(1))) void*)gpB,
                (__attribute__((address_space(3))) void*)(Bs + (size_t)(wave * 64 + s * 256) * 8),
                16, 0, 0);
        }
        __syncthreads();
        short8 af[4], bfr[4];
#pragma unroll
        for (int fi = 0; fi < 4; ++fi)
            af[fi] = *(const short8*)(As + (wm * 64 + fi * 16 + m16) * 32 + kq);
#pragma unroll
        for (int fj = 0; fj < 4; ++fj)
            bfr[fj] = *(const short8*)(Bs + (wn * 64 + fj * 16 + m16) * 32 + kq);
#pragma unroll
        for (int fi = 0; fi < 4; ++fi)
#pragma unroll
            for (int fj = 0; fj < 4; ++fj)
                acc[fi][fj] = __builtin_amdgcn_mfma_f32_16x16x32_bf16(
                    af[fi], bfr[fj], acc[fi][fj], 0, 0, 0);
        __syncthreads();
    }
    // ---- epilogue: per-wave private arena, no further barriers needed ----
    unsigned* my = dyns + wave * (64 * 66);

    float scl[4];
#pragma unroll
    for (int fj = 0; fj < 4; ++fj) scl[fj] = sqz[j0 + wn * 64 + fj * 16 + m16];
    float sr[4][4];
#pragma unroll
    for (int fi = 0; fi < 4; ++fi) {
        float4 s4 = *(const float4*)(sqz + i0 + wm * 64 + fi * 16 + q4 * 4);
        sr[fi][0] = s4.x; sr[fi][1] = s4.y; sr[fi][2] = s4.z; sr[fi][3] = s4.w;
    }

    // orientation A: rows = i-side (wm half), cols = j-side (wn half)
#pragma unroll
    for (int fi = 0; fi < 4; ++fi)
#pragma unroll
        for (int fj = 0; fj < 4; ++fj)
#pragma unroll
            for (int r = 0; r < 4; ++r)
                my[(fi * 16 + q4 * 4 + r) * 66 + (fj * 16 + m16)] =
                    f2key(scl[fj] - 2.f * acc[fi][fj][r]);
    select_emit(my, lane, kc, cc,
                (size_t)z * N_ + i0 + wm * 64 + lane, 2 * bj + wn);

    // orientation B (off-diag): rows = j-side (wn half), cols = i-side (wm half)
    if (bi != bj) {
#pragma unroll
        for (int fi = 0; fi < 4; ++fi)
#pragma unroll
            for (int fj = 0; fj < 4; ++fj)
#pragma unroll
                for (int r = 0; r < 4; ++r)
                    my[(fj * 16 + m16) * 66 + (fi * 16 + q4 * 4 + r)] =
                        f2key(sr[fi][r] - 2.f * acc[fi][fj][r]);
        select_emit(my, lane, kc, cc,
                    (size_t)z * N_ + j0 + wn * 64 + lane, 2 * bi + wm);
    }
}

// ---- merge per-chunk candidates -> exact global top-16 per row ----
// Reads 512 candidates/row (2 KB contiguous, L3-resident), exact lex (value,col).
__global__ __launch_bounds__(256) void topk_cand(const unsigned* __restrict__ kcand,
                                                 const ushort_t* __restrict__ ccand,
                                                 int* __restrict__ idxb) {
    __shared__ unsigned long long cand[4][256];
    __shared__ int cnt[4];
    int w = threadIdx.x >> 6, lane = threadIdx.x & 63;
    int row = blockIdx.x * 4 + w;
    const unsigned* kp = kcand + (size_t)row * 512 + lane * 8;
    uint4 ka = *(const uint4*)(kp);
    uint4 kb = *(const uint4*)(kp + 4);
    unsigned sk[8] = {ka.x, ka.y, ka.z, ka.w, kb.x, kb.y, kb.z, kb.w};
    const ushort_t* cp = ccand + (size_t)row * 512 + lane * 8;
    uint4 cw = *(const uint4*)(cp);
    unsigned cwa[4] = {cw.x, cw.y, cw.z, cw.w};
    unsigned colbase = (unsigned)(lane >> 1) * 64u;
    unsigned long long k2[8];
#pragma unroll
    for (int j = 0; j < 8; ++j) {
        unsigned c = colbase + ((cwa[j >> 1] >> ((j & 1) * 16)) & 0xffffu);
        k2[j] = ((unsigned long long)sk[j] << 32) | c;
    }
    if (lane == 0) cnt[w] = 0;
    unsigned vm = sk[0];
#pragma unroll
    for (int i = 1; i < 8; ++i) vm = min(vm, sk[i]);
#pragma unroll
    for (int k = 2; k <= 64; k <<= 1) {
#pragma unroll
        for (int j = k >> 1; j > 0; j >>= 1) {
            unsigned pv = __shfl_xor(vm, j);
            bool up = ((lane & k) == 0);
            bool lower = ((lane & j) == 0);
            unsigned mn = min(vm, pv), mx = max(vm, pv);
            vm = (lower == up) ? mn : mx;
        }
    }
    unsigned T = __shfl(vm, 15);   // 16th smallest lane-min >= 16th order statistic
    __syncthreads();
#pragma unroll
    for (int j = 0; j < 8; ++j) {
        if (sk[j] <= T) {
            int s = atomicAdd(&cnt[w], 1);
            if (s < 256) cand[w][s] = k2[j];
        }
    }
    __syncthreads();
    int cn = cnt[w];
    if (cn <= 64) {
        unsigned long long mykey = (lane < cn) ? cand[w][lane] : ~0ull;
        for (int it = 0; it < 16; ++it) {
            unsigned long long best = mykey;
#pragma unroll
            for (int off = 32; off; off >>= 1) {
                unsigned long long o = __shfl_xor(best, off);
                if (o < best) best = o;
            }
            if (mykey == best) mykey = ~0ull;
            if (lane == 0) idxb[row * 16 + it] = (int)(unsigned)(best & 0xffffffffu);
        }
    } else if (cn <= 256) {
        for (int it = 0; it < 16; ++it) {
            unsigned long long best = ~0ull;
            for (int i = lane; i < cn; i += 64) {
                unsigned long long c = cand[w][i];
                if (c < best) best = c;
            }
#pragma unroll
            for (int off = 32; off; off >>= 1) {
                unsigned long long o = __shfl_xor(best, off);
                if (o < best) best = o;
            }
            for (int i = lane; i < cn; i += 64)
                if (cand[w][i] == best) cand[w][i] = ~0ull;
            if (lane == 0) idxb[row * 16 + it] = (int)(unsigned)(best & 0xffffffffu);
        }
    } else {
        unsigned msk = 0;
        for (int it = 0; it < 16; ++it) {
            unsigned long long key = ~0ull;
#pragma unroll
            for (int i = 0; i < 8; ++i)
                if (!((msk >> i) & 1u) && k2[i] < key) key = k2[i];
#pragma unroll
            for (int off = 32; off; off >>= 1) {
                unsigned long long o = __shfl_xor(key, off);
                if (o < key) key = o;
            }
#pragma unroll
            for (int i = 0; i < 8; ++i)
                if (k2[i] == key) msk |= 1u << i;
            if (lane == 0) idxb[row * 16 + it] = (int)(unsigned)(key & 0xffffffffu);
        }
    }
}

// t[b,i,h] = uv[row][h] + max_k uv[(b,idx_k)][256+h]; accumulates BN stats of t.
// XCD-pinned: z = blk&7 -> each XCD gathers within its own batch's 2 MB v-half.
__global__ void gather_max(const float* __restrict__ uv, const int* __restrict__ idxb,
                           float* __restrict__ outp, double* __restrict__ stats) {
    int blk = blockIdx.x;
    int b = blk & 7;
    int strip = blk >> 3;               // 0..63
    int r0 = b * N_ + strip * 32;
    int f = threadIdx.x;
    float s1 = 0.f, s2 = 0.f;
    for (int rr = 0; rr < 32; ++rr) {
        int row = r0 + rr;
        const int* ip = idxb + row * 16;
        float m = -FLT_MAX;
#pragma unroll
        for (int k = 0; k < 16; ++k) {
            int j = ip[k];
            m = fmaxf(m, uv[((size_t)((b << 11) + j)) * 512 + 256 + f]);
        }
        float v = uv[(size_t)row * 512 + f] + m;
        outp[(size_t)row * H_ + f] = v;
        s1 += v; s2 += v * v;
    }
    atomicAdd(&stats[f], (double)s1);
    atomicAdd(&stats[H_ + f], (double)s2);
}

// ---- batchnorm helpers ----
__global__ void bn_zero(double* s) { s[threadIdx.x] = 0.0; }

// reads per-feature sums, emits scale/shift, re-zeroes sums for the next user
__global__ void bn_final(double* __restrict__ sums, const float* __restrict__ g,
                         const float* __restrict__ b, float* __restrict__ scsh) {
    int f = threadIdx.x;
    double m  = sums[f] / (double)BN_;
    double var = sums[H_ + f] / (double)BN_ - m * m;
    double inv = 1.0 / sqrt(var + 1e-5);
    float sc = g[f] * (float)inv;
    scsh[f] = sc;
    scsh[H_ + f] = b[f] - (float)m * sc;
    sums[f] = 0.0; sums[H_ + f] = 0.0;
}

// BN+ReLU fused with split-bf16 packing and (optional) row sqnorm reduce.
// Vectorized: one wave = 2 rows, lane owns 8 contiguous features.
__global__ void bn_apply_pack(const float* __restrict__ X, const float* __restrict__ scsh,
                              ushort_t* __restrict__ Ap, float* __restrict__ sq) {
    int tid = threadIdx.x;
    int row = blockIdx.x * 8 + (tid >> 5);
    int f0  = (tid & 31) * 8;
    const float* xp = X + (size_t)row * H_ + f0;
    f32x4 x0 = *(const f32x4*)(xp);
    f32x4 x1 = *(const f32x4*)(xp + 4);
    f32x4 sc0 = *(const f32x4*)(scsh + f0);
    f32x4 sc1 = *(const f32x4*)(scsh + f0 + 4);
    f32x4 sh0 = *(const f32x4*)(scsh + H_ + f0);
    f32x4 sh1 = *(const f32x4*)(scsh + H_ + f0 + 4);
    float v[8];
#pragma unroll
    for (int i = 0; i < 4; ++i) {
        v[i]     = fmaxf(x0[i] * sc0[i] + sh0[i], 0.f);
        v[i + 4] = fmaxf(x1[i] * sc1[i] + sh1[i], 0.f);
    }
    short8 hi8, lo8;
#pragma unroll
    for (int i = 0; i < 8; ++i) {
        ushort_t hi = f2bf(v[i]);
        ushort_t lo = f2bf(v[i] - bf2f(hi));
        hi8[i] = (short)hi; lo8[i] = (short)lo;
    }
    ushort_t* ap = Ap + (size_t)row * KP_ + f0;
    *(short8*)(ap)            = hi8;
    *(short8*)(ap + H_)       = lo8;
    *(short8*)(ap + 2 * H_)   = hi8;
    if (sq) {
        float s = 0.f;
#pragma unroll
        for (int i = 0; i < 8; ++i) s += v[i] * v[i];
#pragma unroll
        for (int off = 16; off; off >>= 1) s += __shfl_down(s, off, 32);
        if ((tid & 31) == 0) sq[row] = s;
    }
}

__global__ void maxpool1(const float* __restrict__ y, float* __restrict__ pmax) {
    int b = blockIdx.x, gc = blockIdx.y, nc = blockIdx.z;
    int g = gc * 256 + threadIdx.x;
    const float* yb = y + ((size_t)b * N_ + (size_t)nc * 128) * G_;
    float m = -FLT_MAX;
    for (int n = 0; n < 128; ++n) m = fmaxf(m, yb[(size_t)n * G_ + g]);
    pmax[((size_t)(b * 16 + nc)) * G_ + g] = m;
}

__global__ void maxpool2(const float* __restrict__ pmax, float* __restrict__ p) {
    int b = blockIdx.x;
    int g = blockIdx.y * 256 + threadIdx.x;
    float m = -FLT_MAX;
    for (int c = 0; c < 16; ++c) m = fmaxf(m, pmax[((size_t)(b * 16 + c)) * G_ + g]);
    p[(size_t)b * G_ + g] = m;
}

// parallel split-K head gemm: grid(M, Nd/64), 256 thr = 64 cols x 4 k-slices
__global__ __launch_bounds__(256) void head_gemm(const float* __restrict__ A,
                                                 const float* __restrict__ W,
                                                 const float* __restrict__ bias,
                                                 float* __restrict__ Cc,
                                                 int Kd, int Nd, int relu) {
    int m = blockIdx.x;
    int c0 = blockIdx.y * 64;
    int cl = threadIdx.x & 63;
    int ks = threadIdx.x >> 6;
    int kper = Kd >> 2;
    const float* Ap = A + (size_t)m * Kd + (size_t)ks * kper;
    const float* Wp = W + (size_t)ks * kper * Nd + c0 + cl;
    float acc = 0.f;
    for (int k = 0; k < kper; k += 8) {
#pragma unroll
        for (int u2 = 0; u2 < 8; ++u2)
            acc += Ap[k + u2] * Wp[(size_t)(k + u2) * Nd];
    }
    __shared__ float red[4][64];
    red[ks][cl] = acc;
    __syncthreads();
    if (ks == 0) {
        float s = red[0][cl] + red[1][cl] + red[2][cl] + red[3][cl] + bias[c0 + cl];
        if (relu) s = fmaxf(s, 0.f);
        Cc[(size_t)m * Nd + c0 + cl] = s;
    }
}

// ---------------- launch ----------------
extern "C" void kernel_launch(void* const* d_in, const int* in_sizes, int n_in,
                              void* d_out, int out_size, void* d_ws, size_t ws_size,
                              hipStream_t stream) {
    (void)in_sizes; (void)n_in; (void)out_size;
    if (ws_size < WS_NEEDED) return;

    const float* x    = (const float*)d_in[0];
    const float* Wf   = (const float*)d_in[2];
    const float* bfv  = (const float*)d_in[3];
    const float* Wnn  = (const float*)d_in[4];
    const float* bnn  = (const float*)d_in[5];
    const float* g1   = (const float*)d_in[6];
    const float* b1   = (const float*)d_in[7];
    const float* We   = (const float*)d_in[8];
    const float* be   = (const float*)d_in[9];
    const float* g2   = (const float*)d_in[10];
    const float* b2   = (const float*)d_in[11];
    const float* Wl   = (const float*)d_in[12];
    const float* bl   = (const float*)d_in[13];
    const float* alpha= (const float*)d_in[14];
    const float* gg   = (const float*)d_in[15];
    const float* bgb  = (const float*)d_in[16];
    const float* Wg   = (const float*)d_in[17];
    const float* bg2  = (const float*)d_in[18];
    const float* Wm1  = (const float*)d_in[19];
    const float* bm1  = (const float*)d_in[20];
    const float* Wm2  = (const float*)d_in[21];
    const float* bm2  = (const float*)d_in[22];
    const float* Wm3  = (const float*)d_in[23];
    const float* bm3  = (const float*)d_in[24];
    float* outp = (float*)d_out;

    char* ws = (char*)d_ws;
    float*    h    = (float*)(ws + OFF_H);
    ushort_t* Ap   = (ushort_t*)(ws + OFF_APACK);
    float*    sqb  = (float*)(ws + OFF_SQ);
    int*      idxb = (int*)  (ws + OFF_IDX);
    double*   stats= (double*)(ws + OFF_STATS);
    float*    scsh = (float*)(ws + OFF_SCSH);
    float*    bcat = (float*)(ws + OFF_BCAT);
    float*    p0   = (float*)(ws + OFF_P0);
    float*    p1   = (float*)(ws + OFF_P1);
    float*    p2   = (float*)(ws + OFF_P2);
    unsigned* kcand= (unsigned*)(ws + OFF_CK);
    ushort_t* ccand= (ushort_t*)(ws + OFF_CC);
    float*    t    = (float*)(ws + OFF_T);
    float*    uv   = (float*)(ws + OFF_UV);
    float*    y    = (float*)(ws + OFF_UV);
    ushort_t* Qw   = (ushort_t*)(ws + OFF_QW);
    float*    pmax = (float*)(ws + OFF_PMAX);

    // one-time zero (ws is re-poisoned before every call); bn_final re-zeroes after use
    hipLaunchKernelGGL(bn_zero, dim3(1), dim3(512), 0, stream, stats);

    // h = x@Wf+bf (+pack), t = h@Wnn+bnn via MFMA (accumulates t-stats), XCD-pinned
    hipLaunchKernelGGL(feat_pack, dim3(BN_), dim3(256), 0, stream, x, Wf, bfv, h, Ap);
    hipLaunchKernelGGL(pack_wT, dim3(H_), dim3(256), 0, stream, Wnn, Qw, H_);
    hipLaunchKernelGGL(mfma_gemm, dim3(256), dim3(256), 0, stream,
                       Ap, Qw, bnn, t, KP_, H_, 0,
                       (const float*)nullptr, (const float*)nullptr, 0, stats, 2);

    for (int l = 0; l < L_; ++l) {
        const float* src1 = (l == 0) ? t : h;
        hipLaunchKernelGGL(bn_final, dim3(1), dim3(256), 0, stream,
                           stats, g1 + l * H_, b1 + l * H_, scsh);
        hipLaunchKernelGGL(bn_apply_pack, dim3(BN_ / 8), dim3(256), 0, stream,
                           src1, scsh, Ap, sqb);
        // symmetric gram + fused per-chunk top-16 candidates (no D materialization)
        hipLaunchKernelGGL(gram_sym, dim3(1088), dim3(256), 67584, stream,
                           Ap, sqb, kcand, ccand);
        hipLaunchKernelGGL(topk_cand, dim3(BN_ / 4), dim3(256), 0, stream,
                           kcand, ccand, idxb);
        // fused u|v gemm (N=512), XCD-pinned
        hipLaunchKernelGGL(pack_qcat, dim3(512), dim3(256), 0, stream,
                           We + (size_t)l * 2 * H_ * H_, be + (size_t)l * H_, Qw, bcat);
        hipLaunchKernelGGL(mfma_gemm, dim3(512), dim3(256), 0, stream,
                           Ap, Qw, bcat, uv, KP_, 512, 0,
                           (const float*)nullptr, (const float*)nullptr, 0,
                           (double*)nullptr, 4);
        hipLaunchKernelGGL(gather_max, dim3(512), dim3(256), 0, stream,
                           uv, idxb, t, stats);
        // BN2 + Wl with fused residual: h = h + alpha[l]*(xb@Wl + bl) (+h-stats)
        hipLaunchKernelGGL(bn_final, dim3(1), dim3(256), 0, stream,
                           stats, g2 + l * H_, b2 + l * H_, scsh);
        hipLaunchKernelGGL(bn_apply_pack, dim3(BN_ / 8), dim3(256), 0, stream,
                           t, scsh, Ap, (float*)nullptr);
        hipLaunchKernelGGL(pack_wT, dim3(H_), dim3(256), 0, stream,
                           Wl + (size_t)l * H_ * H_, Qw, H_);
        hipLaunchKernelGGL(mfma_gemm, dim3(256), dim3(256), 0, stream,
                           Ap, Qw, bl + (size_t)l * H_, h, KP_, H_, 2,
                           h, alpha, l, stats, 2);
    }

    // head
    hipLaunchKernelGGL(bn_final, dim3(1), dim3(256), 0, stream, stats, gg, bgb, scsh);
    hipLaunchKernelGGL(bn_apply_pack, dim3(BN_ / 8), dim3(256), 0, stream,
                       h, scsh, Ap, (float*)nullptr);
    hipLaunchKernelGGL(pack_wT, dim3(G_), dim3(256), 0, stream, Wg, Qw, G_);
    hipLaunchKernelGGL(mfma_gemm, dim3(512), dim3(256), 0, stream,
                       Ap, Qw, bg2, y, KP_, G_, 0,
                       (const float*)nullptr, (const float*)nullptr, 0,
                       (double*)nullptr, 4);
    hipLaunchKernelGGL(maxpool1, dim3(8, 2, 16), dim3(256), 0, stream, y, pmax);
    hipLaunchKernelGGL(maxpool2, dim3(8, 2), dim3(256), 0, stream, pmax, p0);
    hipLaunchKernelGGL(head_gemm, dim3(8, 4), dim3(256), 0, stream, p0, Wm1, bm1, p1, G_, M0_, 1);
    hipLaunchKernelGGL(head_gemm, dim3(8, 2), dim3(256), 0, stream, p1, Wm2, bm2, p2, M0_, M1_, 1);
    hipLaunchKernelGGL(head_gemm, dim3(8, 2), dim3(256), 0, stream, p2, Wm3, bm3, outp, M1_, C_, 0);
}

// Round 2
// 1233.227 us; speedup vs baseline: 1.1276x; 1.1276x over previous
//
#include <hip/hip_runtime.h>
#include <cfloat>

#define B_  8
#define N_  2048
#define H_  256
#define L_  4
#define K_  16
#define G_  512
#define M0_ 256
#define M1_ 128
#define C_  128
#define BN_ 16384   // B_*N_
#define KP_ 768     // packed split-bf16 K (3*H_)

typedef unsigned short ushort_t;
typedef __attribute__((ext_vector_type(8))) short short8;
typedef __attribute__((ext_vector_type(4))) float f32x4;

// ---------------- workspace layout (bytes) ----------------
#define OFF_H     ((size_t)0)            // 16 MB  h (fp32, persistent)
#define OFF_APACK ((size_t)16777216)     // 25.2 MB  P-pack [hi,lo,hi] (Q read via seg remap)
#define OFF_MIND  ((size_t)46137344)     // 4 MB  per-(row, 32col-chunk) min keys u32 [16384][64]
#define OFF_SQ    ((size_t)67108864)     // 64 KB
#define OFF_IDX   ((size_t)67174400)     // 1 MB
#define OFF_STATS ((size_t)68222976)     // 4 KB (512 doubles)
#define OFF_SCSH  ((size_t)68227072)     // 2 KB
#define OFF_BCAT  ((size_t)68229120)     // 2 KB
#define OFF_P0    ((size_t)68231168)     // 16 KB
#define OFF_P1    ((size_t)68247552)
#define OFF_P2    ((size_t)68255744)
#define OFF_D     ((size_t)69206016)     // 134.2 MB dmat; overlays below (stream-ordered safe)
#define OFF_T     (OFF_D + (size_t)0)           // 16 MB (alive gather_max -> bn2; dmat dead)
#define OFF_UV    (OFF_D + (size_t)50331648)    // 33.5 MB (alive uv gemm -> gather); also y
#define OFF_QW    (OFF_D + (size_t)83886080)    // 0.79 MB weight packs
#define OFF_PMAX  (OFF_D + (size_t)84672512)    // 256 KB
#define WS_NEEDED ((size_t)203423744)

// ---------------- helpers ----------------
static __device__ __forceinline__ ushort_t f2bf(float f) {
    unsigned u = __float_as_uint(f);
    unsigned r = (u + 0x7fffu + ((u >> 16) & 1u)) >> 16;   // RNE
    return (ushort_t)r;
}
static __device__ __forceinline__ float bf2f(ushort_t h) {
    return __uint_as_float(((unsigned)h) << 16);
}
// monotone f32 -> u32 sortkey (same transform as topk16 screen)
static __device__ __forceinline__ unsigned f2key(float f) {
    unsigned u = __float_as_uint(f);
    return (u & 0x80000000u) ? ~u : (u | 0x80000000u);
}
// P-pack layout per row: [hi(0:256), lo(256:512), hi(512:768)]
static __device__ __forceinline__ void pack3(float v, ushort_t* A, size_t base, int f) {
    ushort_t hi = f2bf(v);
    ushort_t lo = f2bf(v - bf2f(hi));
    A[base + f] = hi; A[base + H_ + f] = lo; A[base + 2 * H_ + f] = hi;
}

// ---------------- kernels ----------------

// h = x @ Wf + bf ; also pack h into Apack
__global__ void feat_pack(const float* __restrict__ x, const float* __restrict__ Wf,
                          const float* __restrict__ bfv, float* __restrict__ h,
                          ushort_t* __restrict__ Ap) {
    int pt = blockIdx.x;
    int f  = threadIdx.x;
    float x0 = x[pt * 3 + 0], x1 = x[pt * 3 + 1], x2 = x[pt * 3 + 2];
    float v = x0 * Wf[f] + x1 * Wf[H_ + f] + x2 * Wf[2 * H_ + f] + bfv[f];
    h[(size_t)pt * H_ + f] = v;
    pack3(v, Ap, (size_t)pt * KP_, f);
}

// W (256 x Nd) -> Qpack (Nd x 768) rows [hi,hi,lo] of W^T
__global__ void pack_wT(const float* __restrict__ W, ushort_t* __restrict__ Qp, int Nd) {
    int n = blockIdx.x, k = threadIdx.x;
    float w = W[(size_t)k * Nd + n];
    ushort_t hi = f2bf(w), lo = f2bf(w - bf2f(hi));
    size_t base = (size_t)n * KP_;
    Qp[base + k] = hi; Qp[base + H_ + k] = hi; Qp[base + 2 * H_ + k] = lo;
}

// Qcat for fused u|v gemm: rows 0..255 = (We_a - We_b)^T, rows 256..511 = We_b^T
__global__ void pack_qcat(const float* __restrict__ We_l, const float* __restrict__ be_l,
                          ushort_t* __restrict__ Qp, float* __restrict__ bcat) {
    int n = blockIdx.x, k = threadIdx.x;
    float w;
    if (n < H_) w = We_l[(size_t)k * H_ + n] - We_l[(size_t)H_ * H_ + (size_t)k * H_ + n];
    else        w = We_l[(size_t)H_ * H_ + (size_t)k * H_ + (n - H_)];
    ushort_t hi = f2bf(w), lo = f2bf(w - bf2f(hi));
    size_t base = (size_t)n * KP_;
    Qp[base + k] = hi; Qp[base + H_ + k] = hi; Qp[base + 2 * H_ + k] = lo;
    if (k == 0) bcat[n] = (n < H_) ? be_l[n] : 0.f;
}

// ---- split-bf16 MFMA GEMM: out = P (M x K) . Q^T (N x K) ----
// mode 0: out[r][c] = acc + aux[c]
// mode 2: out[r][c] = resid[r][c] + alphap[aidx]*(acc+aux[c])
// stats != nullptr: accumulate per-column sum/sumsq of written values (BN prestats)
// nx != 0: 1-D grid of nx*128 blocks, XCD-pinned: z=blk&7 owns M-rows of batch z.
__global__ __launch_bounds__(256) void mfma_gemm(
    const ushort_t* __restrict__ P, const ushort_t* __restrict__ Q,
    const float* __restrict__ aux, float* __restrict__ out,
    int Kd, int ldOut, int mode, const float* __restrict__ resid,
    const float* __restrict__ alphap, int aidx, double* __restrict__ stats,
    int nx) {
    __shared__ __align__(16) ushort_t As[128 * 32];
    __shared__ __align__(16) ushort_t Bs[128 * 32];
    __shared__ float cs1[4][64], cs2[4][64];
    int i0, j0;
    if (nx) {
        int blk = blockIdx.x;
        int z = blk & 7;
        int rest = blk >> 3;
        int xb = rest % nx;
        int ys = rest / nx;            // 0..15
        i0 = (z * 16 + ys) * 128;
        j0 = xb * 128;
    } else {
        i0 = blockIdx.y * 128; j0 = blockIdx.x * 128;
    }
    int tid = threadIdx.x;
    int lane = tid & 63, wave = tid >> 6;
    int wm = wave & 1, wn = wave >> 1;
    int m16 = lane & 15, kq = (lane >> 4) * 8;

    f32x4 acc[4][4];
    f32x4 zero = {0.f, 0.f, 0.f, 0.f};
#pragma unroll
    for (int i = 0; i < 4; ++i)
#pragma unroll
        for (int j = 0; j < 4; ++j) acc[i][j] = zero;

    int srow = tid >> 2;
    int skc  = (tid & 3) * 8;

    for (int k0 = 0; k0 < Kd; k0 += 32) {
#pragma unroll
        for (int s = 0; s < 2; ++s) {
            int row = srow + s * 64;
            const ushort_t* gpA = P + (size_t)(i0 + row) * Kd + k0 + skc;
            const ushort_t* gpB = Q + (size_t)(j0 + row) * Kd + k0 + skc;
            __builtin_amdgcn_global_load_lds(
                (const __attribute__((address_space(1))) void*)gpA,
                (__attribute__((address_space(3))) void*)(As + (size_t)(wave * 64 + s * 256) * 8),
                16, 0, 0);
            __builtin_amdgcn_global_load_lds(
                (const __attribute__((address_space(1))) void*)gpB,
                (__attribute__((address_space(3))) void*)(Bs + (size_t)(wave * 64 + s * 256) * 8),
                16, 0, 0);
        }
        __syncthreads();
        short8 af[4], bfr[4];
#pragma unroll
        for (int fi = 0; fi < 4; ++fi)
            af[fi] = *(const short8*)(As + (wm * 64 + fi * 16 + m16) * 32 + kq);
#pragma unroll
        for (int fj = 0; fj < 4; ++fj)
            bfr[fj] = *(const short8*)(Bs + (wn * 64 + fj * 16 + m16) * 32 + kq);
#pragma unroll
        for (int fi = 0; fi < 4; ++fi)
#pragma unroll
            for (int fj = 0; fj < 4; ++fj)
                acc[fi][fj] = __builtin_amdgcn_mfma_f32_16x16x32_bf16(
                    af[fi], bfr[fj], acc[fi][fj], 0, 0, 0);
        __syncthreads();
    }
    float alpha = (mode == 2) ? alphap[aidx] : 0.f;
    int rbase = i0 + wm * 64 + (lane >> 4) * 4;
    int cbase = j0 + wn * 64 + m16;
    float s1[4] = {0.f, 0.f, 0.f, 0.f}, s2[4] = {0.f, 0.f, 0.f, 0.f};
#pragma unroll
    for (int fi = 0; fi < 4; ++fi) {
#pragma unroll
        for (int fj = 0; fj < 4; ++fj) {
            int c = cbase + fj * 16;
            float a = aux[c];
#pragma unroll
            for (int r = 0; r < 4; ++r) {
                int gr = rbase + fi * 16 + r;
                size_t oidx = (size_t)gr * ldOut + c;
                float val;
                if (mode == 2) val = resid[oidx] + alpha * (acc[fi][fj][r] + a);
                else           val = acc[fi][fj][r] + a;
                out[oidx] = val;
                s1[fj] += val; s2[fj] += val * val;
            }
        }
    }
    if (stats) {
#pragma unroll
        for (int fj = 0; fj < 4; ++fj) {
            float a1 = s1[fj], a2 = s2[fj];
            a1 += __shfl_xor(a1, 16); a1 += __shfl_xor(a1, 32);
            a2 += __shfl_xor(a2, 16); a2 += __shfl_xor(a2, 32);
            if ((lane >> 4) == 0) {
                cs1[wave][fj * 16 + m16] = a1;
                cs2[wave][fj * 16 + m16] = a2;
            }
        }
        __syncthreads();
        if (tid < 128) {
            int wnl = tid >> 6, cl = tid & 63;
            float t1 = cs1[2 * wnl][cl] + cs1[2 * wnl + 1][cl];
            float t2 = cs2[2 * wnl][cl] + cs2[2 * wnl + 1][cl];
            int c = j0 + tid;
            atomicAdd(&stats[c], (double)t1);
            atomicAdd(&stats[H_ + c], (double)t2);
        }
    }
}

// ---- symmetric gram: D[i][j] = sq[j] - 2 <x_i, x_j>, upper-tri tile pairs only ----
// 1-D grid 1088: z = blk&7 (XCD pin), p = blk>>3 enumerates bi<=bj tile pairs.
// B-side reads P-pack with segment remap (0,2,1).
// Epilogue: wave-private LDS transpose -> f32x4 NT stores (Round-0 known-good),
// PLUS per-(row, 32col-chunk) min keys into minD (register-only butterflies):
// lets topk16 skip chunks whose min key > screen threshold.
__global__ __launch_bounds__(256) void gram_sym(const ushort_t* __restrict__ Ap,
                                                const float* __restrict__ sqb,
                                                float* __restrict__ D,
                                                unsigned* __restrict__ minD) {
    __shared__ __align__(16) ushort_t As[128 * 32];
    __shared__ __align__(16) ushort_t Bs[128 * 32];
    __shared__ __align__(16) float stg[4][1280];   // wave-private transpose pool
    int blk = blockIdx.x;
    int z = blk & 7;
    int p = blk >> 3;
    int bi = 0, rem = p;
    while (rem >= 16 - bi) { rem -= 16 - bi; ++bi; }
    int bj = bi + rem;
    const ushort_t* Pz = Ap + (size_t)z * N_ * KP_;
    const float* sqz = sqb + (size_t)z * N_;
    float* Dz = D + (size_t)z * N_ * N_;
    int i0 = bi * 128, j0 = bj * 128;

    int tid = threadIdx.x;
    int lane = tid & 63, wave = tid >> 6;
    int wm = wave & 1, wn = wave >> 1;
    int m16 = lane & 15, q4 = lane >> 4;
    int kq = q4 * 8;

    f32x4 acc[4][4];
    f32x4 zero = {0.f, 0.f, 0.f, 0.f};
#pragma unroll
    for (int i = 0; i < 4; ++i)
#pragma unroll
        for (int j = 0; j < 4; ++j) acc[i][j] = zero;

    int srow = tid >> 2;
    int skc  = (tid & 3) * 8;

    for (int k0 = 0; k0 < KP_; k0 += 32) {
        // Q segment remap: seg0->seg0(hi), seg1->seg2(hi), seg2->seg1(lo)
        int kb = (k0 < 256) ? k0 : ((k0 < 512) ? k0 + 256 : k0 - 256);
#pragma unroll
        for (int s = 0; s < 2; ++s) {
            int row = srow + s * 64;
            const ushort_t* gpA = Pz + (size_t)(i0 + row) * KP_ + k0 + skc;
            const ushort_t* gpB = Pz + (size_t)(j0 + row) * KP_ + kb + skc;
            __builtin_amdgcn_global_load_lds(
                (const __attribute__((address_space(1))) void*)gpA,
                (__attribute__((address_space(3))) void*)(As + (size_t)(wave * 64 + s * 256) * 8),
                16, 0, 0);
            __builtin_amdgcn_global_load_lds(
                (const __attribute__((address_space(1))) void*)gpB,
                (__attribute__((address_space(3))) void*)(Bs + (size_t)(wave * 64 + s * 256) * 8),
                16, 0, 0);
        }
        __syncthreads();
        short8 af[4], bfr[4];
#pragma unroll
        for (int fi = 0; fi < 4; ++fi)
            af[fi] = *(const short8*)(As + (wm * 64 + fi * 16 + m16) * 32 + kq);
#pragma unroll
        for (int fj = 0; fj < 4; ++fj)
            bfr[fj] = *(const short8*)(Bs + (wn * 64 + fj * 16 + m16) * 32 + kq);
#pragma unroll
        for (int fi = 0; fi < 4; ++fi)
#pragma unroll
            for (int fj = 0; fj < 4; ++fj)
                acc[fi][fj] = __builtin_amdgcn_mfma_f32_16x16x32_bf16(
                    af[fi], bfr[fj], acc[fi][fj], 0, 0, 0);
        __syncthreads();
    }

    float* sg = stg[wave];
    float scl[4];
#pragma unroll
    for (int fj = 0; fj < 4; ++fj) scl[fj] = sqz[j0 + wn * 64 + fj * 16 + m16];
    float sr[4][4];
#pragma unroll
    for (int fi = 0; fi < 4; ++fi) {
        float4 s4 = *(const float4*)(sqz + i0 + wm * 64 + fi * 16 + q4 * 4);
        sr[fi][0] = s4.x; sr[fi][1] = s4.y; sr[fi][2] = s4.z; sr[fi][3] = s4.w;
    }

    // normal orientation: per fi, wave-private [16][68] transpose -> f32x4 stores
    int rr = lane >> 2, cc = lane & 3;
#pragma unroll
    for (int fi = 0; fi < 4; ++fi) {
#pragma unroll
        for (int fj = 0; fj < 4; ++fj)
#pragma unroll
            for (int r = 0; r < 4; ++r)
                sg[(q4 * 4 + r) * 68 + fj * 16 + m16] = scl[fj] - 2.f * acc[fi][fj][r];
        float* drow = Dz + (size_t)(i0 + wm * 64 + fi * 16 + rr) * N_ + j0 + wn * 64;
#pragma unroll
        for (int t = 0; t < 4; ++t) {
            int chunk = cc + 4 * t;
            f32x4 o = *(const f32x4*)(sg + rr * 68 + chunk * 4);
            __builtin_nontemporal_store(o, (f32x4*)(drow + chunk * 4));
        }
    }

    // chunk-min emission, orientation A: rows = i-side, 2 chunks on j-side
    // (computed in key space: unsigned min is tie/-0 safe)
#pragma unroll
    for (int fi = 0; fi < 4; ++fi) {
        unsigned c0k[4], c1k[4];
#pragma unroll
        for (int r = 0; r < 4; ++r) {
            unsigned k0m = min(f2key(scl[0] - 2.f * acc[fi][0][r]),
                               f2key(scl[1] - 2.f * acc[fi][1][r]));
            unsigned k1m = min(f2key(scl[2] - 2.f * acc[fi][2][r]),
                               f2key(scl[3] - 2.f * acc[fi][3][r]));
#pragma unroll
            for (int off = 1; off <= 8; off <<= 1) {
                k0m = min(k0m, (unsigned)__shfl_xor((int)k0m, off));
                k1m = min(k1m, (unsigned)__shfl_xor((int)k1m, off));
            }
            c0k[r] = k0m; c1k[r] = k1m;
        }
        if (m16 == 0) {
            size_t mb = ((size_t)z * N_ + i0 + wm * 64 + fi * 16 + q4 * 4) * 64
                        + (size_t)(bj * 4 + wn * 2);
#pragma unroll
            for (int r = 0; r < 4; ++r) {
                minD[mb + (size_t)r * 64]     = c0k[r];
                minD[mb + (size_t)r * 64 + 1] = c1k[r];
            }
        }
    }

    // transposed orientation (off-diag): per fi, wave-private [64][20] -> f32x4 stores
    if (bi != bj) {
#pragma unroll
        for (int fi = 0; fi < 4; ++fi) {
#pragma unroll
            for (int fj = 0; fj < 4; ++fj)
#pragma unroll
                for (int r = 0; r < 4; ++r)
                    sg[(fj * 16 + m16) * 20 + q4 * 4 + r] =
                        sr[fi][r] - 2.f * acc[fi][fj][r];
            int chunk = lane & 3;
#pragma unroll
            for (int u = 0; u < 4; ++u) {
                int cr = (lane >> 2) + 16 * u;
                f32x4 o = *(const f32x4*)(sg + cr * 20 + chunk * 4);
                __builtin_nontemporal_store(o,
                    (f32x4*)(Dz + (size_t)(j0 + wn * 64 + cr) * N_ +
                             i0 + wm * 64 + fi * 16 + chunk * 4));
            }
        }

        // chunk-min emission, orientation B: rows = j-side, 2 chunks on i-side
#pragma unroll
        for (int fj = 0; fj < 4; ++fj) {
            unsigned k0m = 0xFFFFFFFFu, k1m = 0xFFFFFFFFu;
#pragma unroll
            for (int fi = 0; fi < 2; ++fi)
#pragma unroll
                for (int r = 0; r < 4; ++r) {
                    k0m = min(k0m, f2key(sr[fi][r]     - 2.f * acc[fi][fj][r]));
                    k1m = min(k1m, f2key(sr[fi + 2][r] - 2.f * acc[fi + 2][fj][r]));
                }
            k0m = min(k0m, (unsigned)__shfl_xor((int)k0m, 16));
            k0m = min(k0m, (unsigned)__shfl_xor((int)k0m, 32));
            k1m = min(k1m, (unsigned)__shfl_xor((int)k1m, 16));
            k1m = min(k1m, (unsigned)__shfl_xor((int)k1m, 32));
            if (q4 == 0) {
                size_t mb = ((size_t)z * N_ + j0 + wn * 64 + fj * 16 + m16) * 64
                            + (size_t)(bi * 4 + wm * 2);
                minD[mb]     = k0m;
                minD[mb + 1] = k1m;
            }
        }
    }
}

// ---- threshold top-16 smallest per row (exact, lex (value,col) tie-break) ----
// v2: screen via per-32col-chunk min keys: T = 16th smallest of the row's 64
// chunk mins (>= 16th order statistic). Only chunks with min <= T are read
// (~16-20 of 64). Candidates {key <= T} extracted with the proven 3-tier paths.
__global__ __launch_bounds__(256) void topk16(const float* __restrict__ D,
                                              const unsigned* __restrict__ minD,
                                              int* __restrict__ idxb) {
    __shared__ unsigned long long cand[4][256];
    __shared__ int cnt[4];
    int w = threadIdx.x >> 6, lane = threadIdx.x & 63;
    int row = blockIdx.x * 4 + w;
    const float* dp = D + (size_t)row * N_;
    unsigned mv = minD[(size_t)row * 64 + lane];
    if (lane == 0) cnt[w] = 0;
    unsigned vm = mv;
#pragma unroll
    for (int k = 2; k <= 64; k <<= 1) {
#pragma unroll
        for (int j = k >> 1; j > 0; j >>= 1) {
            unsigned pv = __shfl_xor(vm, j);
            bool up = ((lane & k) == 0);
            bool lower = ((lane & j) == 0);
            unsigned mn = min(vm, pv), mx = max(vm, pv);
            vm = (lower == up) ? mn : mx;
        }
    }
    unsigned T = __shfl(vm, 15);   // 16th smallest chunk-min >= 16th order statistic
    unsigned long long cmask = __ballot(mv <= T);
    __syncthreads();
    int nc = __popcll(cmask);
    unsigned long long mrem = cmask;
    unsigned long long lowmask = (1ull << lane) - 1ull;
    for (int it = 0; it < nc; it += 2) {
        int c0 = __ffsll(mrem) - 1; mrem &= mrem - 1ull;
        int c1 = -1;
        if (it + 1 < nc) { c1 = __ffsll(mrem) - 1; mrem &= mrem - 1ull; }
        int c = (lane < 32) ? c0 : c1;
        bool act = (c >= 0);
        float dv = act ? dp[c * 32 + (lane & 31)] : 0.f;
        unsigned kk2 = f2key(dv);
        bool sel = act && (kk2 <= T);
        unsigned long long bal = __ballot(sel);
        int tot = __popcll(bal);
        int rk  = __popcll(bal & lowmask);
        int base = 0;
        if (lane == 0) base = atomicAdd(&cnt[w], tot);
        base = __shfl(base, 0);
        int s = base + rk;
        if (sel && s < 256)
            cand[w][s] = ((unsigned long long)kk2 << 32) |
                         (unsigned)(c * 32 + (lane & 31));
    }
    __syncthreads();
    int cn = cnt[w];
    if (cn <= 64) {
        unsigned long long mykey = (lane < cn) ? cand[w][lane] : ~0ull;
        for (int it = 0; it < 16; ++it) {
            unsigned long long best = mykey;
#pragma unroll
            for (int off = 32; off; off >>= 1) {
                unsigned long long o = __shfl_xor(best, off);
                if (o < best) best = o;
            }
            if (mykey == best) mykey = ~0ull;
            if (lane == 0) idxb[row * 16 + it] = (int)(unsigned)(best & 0xffffffffu);
        }
    } else if (cn <= 256) {
        for (int it = 0; it < 16; ++it) {
            unsigned long long best = ~0ull;
            for (int i = lane; i < cn; i += 64) {
                unsigned long long c = cand[w][i];
                if (c < best) best = c;
            }
#pragma unroll
            for (int off = 32; off; off >>= 1) {
                unsigned long long o = __shfl_xor(best, off);
                if (o < best) best = o;
            }
            for (int i = lane; i < cn; i += 64)
                if (cand[w][i] == best) cand[w][i] = ~0ull;
            if (lane == 0) idxb[row * 16 + it] = (int)(unsigned)(best & 0xffffffffu);
        }
    } else {
        // rare fallback: re-read full row, masked 16-round extraction
        unsigned sk[32];
#pragma unroll
        for (int t = 0; t < 8; ++t) {
            f32x4 v4 = __builtin_nontemporal_load((const f32x4*)(dp + t * 256 + lane * 4));
#pragma unroll
            for (int j = 0; j < 4; ++j) sk[t * 4 + j] = f2key(v4[j]);
        }
        unsigned mask = 0;
        for (int it = 0; it < 16; ++it) {
            unsigned long long key = ~0ull;
#pragma unroll
            for (int i = 0; i < 32; ++i) {
                if (!((mask >> i) & 1u)) {
                    unsigned long long k2 = ((unsigned long long)sk[i] << 32) |
                        (unsigned)((i >> 2) * 256 + lane * 4 + (i & 3));
                    if (k2 < key) key = k2;
                }
            }
#pragma unroll
            for (int off = 32; off; off >>= 1) {
                unsigned long long o = __shfl_xor(key, off);
                if (o < key) key = o;
            }
            unsigned jc = (unsigned)(key & 0xffffffffu);
            int li = ((jc & 255) >> 2);
            int ii = ((jc >> 8) << 2) | (jc & 3);
            if (lane == li) mask |= 1u << ii;
            if (lane == 0) idxb[row * 16 + it] = (int)jc;
        }
    }
}

// t[b,i,h] = uv[row][h] + max_k uv[(b,idx_k)][256+h]; accumulates BN stats of t.
// XCD-pinned: z = blk&7 -> each XCD gathers within its own batch's 2 MB v-half.
__global__ void gather_max(const float* __restrict__ uv, const int* __restrict__ idxb,
                           float* __restrict__ outp, double* __restrict__ stats) {
    int blk = blockIdx.x;
    int b = blk & 7;
    int strip = blk >> 3;               // 0..63
    int r0 = b * N_ + strip * 32;
    int f = threadIdx.x;
    float s1 = 0.f, s2 = 0.f;
    for (int rr = 0; rr < 32; ++rr) {
        int row = r0 + rr;
        const int* ip = idxb + row * 16;
        float m = -FLT_MAX;
#pragma unroll
        for (int k = 0; k < 16; ++k) {
            int j = ip[k];
            m = fmaxf(m, uv[((size_t)((b << 11) + j)) * 512 + 256 + f]);
        }
        float v = uv[(size_t)row * 512 + f] + m;
        outp[(size_t)row * H_ + f] = v;
        s1 += v; s2 += v * v;
    }
    atomicAdd(&stats[f], (double)s1);
    atomicAdd(&stats[H_ + f], (double)s2);
}

// ---- batchnorm helpers ----
__global__ void bn_zero(double* s) { s[threadIdx.x] = 0.0; }

// reads per-feature sums, emits scale/shift, re-zeroes sums for the next user
__global__ void bn_final(double* __restrict__ sums, const float* __restrict__ g,
                         const float* __restrict__ b, float* __restrict__ scsh) {
    int f = threadIdx.x;
    double m  = sums[f] / (double)BN_;
    double var = sums[H_ + f] / (double)BN_ - m * m;
    double inv = 1.0 / sqrt(var + 1e-5);
    float sc = g[f] * (float)inv;
    scsh[f] = sc;
    scsh[H_ + f] = b[f] - (float)m * sc;
    sums[f] = 0.0; sums[H_ + f] = 0.0;
}

// BN+ReLU fused with split-bf16 packing and (optional) row sqnorm reduce.
// Vectorized: one wave = 2 rows, lane owns 8 contiguous features.
__global__ void bn_apply_pack(const float* __restrict__ X, const float* __restrict__ scsh,
                              ushort_t* __restrict__ Ap, float* __restrict__ sq) {
    int tid = threadIdx.x;
    int row = blockIdx.x * 8 + (tid >> 5);
    int f0  = (tid & 31) * 8;
    const float* xp = X + (size_t)row * H_ + f0;
    f32x4 x0 = *(const f32x4*)(xp);
    f32x4 x1 = *(const f32x4*)(xp + 4);
    f32x4 sc0 = *(const f32x4*)(scsh + f0);
    f32x4 sc1 = *(const f32x4*)(scsh + f0 + 4);
    f32x4 sh0 = *(const f32x4*)(scsh + H_ + f0);
    f32x4 sh1 = *(const f32x4*)(scsh + H_ + f0 + 4);
    float v[8];
#pragma unroll
    for (int i = 0; i < 4; ++i) {
        v[i]     = fmaxf(x0[i] * sc0[i] + sh0[i], 0.f);
        v[i + 4] = fmaxf(x1[i] * sc1[i] + sh1[i], 0.f);
    }
    short8 hi8, lo8;
#pragma unroll
    for (int i = 0; i < 8; ++i) {
        ushort_t hi = f2bf(v[i]);
        ushort_t lo = f2bf(v[i] - bf2f(hi));
        hi8[i] = (short)hi; lo8[i] = (short)lo;
    }
    ushort_t* ap = Ap + (size_t)row * KP_ + f0;
    *(short8*)(ap)            = hi8;
    *(short8*)(ap + H_)       = lo8;
    *(short8*)(ap + 2 * H_)   = hi8;
    if (sq) {
        float s = 0.f;
#pragma unroll
        for (int i = 0; i < 8; ++i) s += v[i] * v[i];
#pragma unroll
        for (int off = 16; off; off >>= 1) s += __shfl_down(s, off, 32);
        if ((tid & 31) == 0) sq[row] = s;
    }
}

__global__ void maxpool1(const float* __restrict__ y, float* __restrict__ pmax) {
    int b = blockIdx.x, gc = blockIdx.y, nc = blockIdx.z;
    int g = gc * 256 + threadIdx.x;
    const float* yb = y + ((size_t)b * N_ + (size_t)nc * 128) * G_;
    float m = -FLT_MAX;
    for (int n = 0; n < 128; ++n) m = fmaxf(m, yb[(size_t)n * G_ + g]);
    pmax[((size_t)(b * 16 + nc)) * G_ + g] = m;
}

__global__ void maxpool2(const float* __restrict__ pmax, float* __restrict__ p) {
    int b = blockIdx.x;
    int g = blockIdx.y * 256 + threadIdx.x;
    float m = -FLT_MAX;
    for (int c = 0; c < 16; ++c) m = fmaxf(m, pmax[((size_t)(b * 16 + c)) * G_ + g]);
    p[(size_t)b * G_ + g] = m;
}

// parallel split-K head gemm: grid(M, Nd/64), 256 thr = 64 cols x 4 k-slices
__global__ __launch_bounds__(256) void head_gemm(const float* __restrict__ A,
                                                 const float* __restrict__ W,
                                                 const float* __restrict__ bias,
                                                 float* __restrict__ Cc,
                                                 int Kd, int Nd, int relu) {
    int m = blockIdx.x;
    int c0 = blockIdx.y * 64;
    int cl = threadIdx.x & 63;
    int ks = threadIdx.x >> 6;
    int kper = Kd >> 2;
    const float* Ap = A + (size_t)m * Kd + (size_t)ks * kper;
    const float* Wp = W + (size_t)ks * kper * Nd + c0 + cl;
    float acc = 0.f;
    for (int k = 0; k < kper; k += 8) {
#pragma unroll
        for (int u2 = 0; u2 < 8; ++u2)
            acc += Ap[k + u2] * Wp[(size_t)(k + u2) * Nd];
    }
    __shared__ float red[4][64];
    red[ks][cl] = acc;
    __syncthreads();
    if (ks == 0) {
        float s = red[0][cl] + red[1][cl] + red[2][cl] + red[3][cl] + bias[c0 + cl];
        if (relu) s = fmaxf(s, 0.f);
        Cc[(size_t)m * Nd + c0 + cl] = s;
    }
}

// ---------------- launch ----------------
extern "C" void kernel_launch(void* const* d_in, const int* in_sizes, int n_in,
                              void* d_out, int out_size, void* d_ws, size_t ws_size,
                              hipStream_t stream) {
    (void)in_sizes; (void)n_in; (void)out_size;
    if (ws_size < WS_NEEDED) return;

    const float* x    = (const float*)d_in[0];
    const float* Wf   = (const float*)d_in[2];
    const float* bfv  = (const float*)d_in[3];
    const float* Wnn  = (const float*)d_in[4];
    const float* bnn  = (const float*)d_in[5];
    const float* g1   = (const float*)d_in[6];
    const float* b1   = (const float*)d_in[7];
    const float* We   = (const float*)d_in[8];
    const float* be   = (const float*)d_in[9];
    const float* g2   = (const float*)d_in[10];
    const float* b2   = (const float*)d_in[11];
    const float* Wl   = (const float*)d_in[12];
    const float* bl   = (const float*)d_in[13];
    const float* alpha= (const float*)d_in[14];
    const float* gg   = (const float*)d_in[15];
    const float* bgb  = (const float*)d_in[16];
    const float* Wg   = (const float*)d_in[17];
    const float* bg2  = (const float*)d_in[18];
    const float* Wm1  = (const float*)d_in[19];
    const float* bm1  = (const float*)d_in[20];
    const float* Wm2  = (const float*)d_in[21];
    const float* bm2  = (const float*)d_in[22];
    const float* Wm3  = (const float*)d_in[23];
    const float* bm3  = (const float*)d_in[24];
    float* outp = (float*)d_out;

    char* ws = (char*)d_ws;
    float*    h    = (float*)(ws + OFF_H);
    ushort_t* Ap   = (ushort_t*)(ws + OFF_APACK);
    unsigned* minDp= (unsigned*)(ws + OFF_MIND);
    float*    sqb  = (float*)(ws + OFF_SQ);
    int*      idxb = (int*)  (ws + OFF_IDX);
    double*   stats= (double*)(ws + OFF_STATS);
    float*    scsh = (float*)(ws + OFF_SCSH);
    float*    bcat = (float*)(ws + OFF_BCAT);
    float*    p0   = (float*)(ws + OFF_P0);
    float*    p1   = (float*)(ws + OFF_P1);
    float*    p2   = (float*)(ws + OFF_P2);
    float*    dmat = (float*)(ws + OFF_D);
    float*    t    = (float*)(ws + OFF_T);
    float*    uv   = (float*)(ws + OFF_UV);
    float*    y    = (float*)(ws + OFF_UV);
    ushort_t* Qw   = (ushort_t*)(ws + OFF_QW);
    float*    pmax = (float*)(ws + OFF_PMAX);

    // one-time zero (ws is re-poisoned before every call); bn_final re-zeroes after use
    hipLaunchKernelGGL(bn_zero, dim3(1), dim3(512), 0, stream, stats);

    // h = x@Wf+bf (+pack), t = h@Wnn+bnn via MFMA (accumulates t-stats), XCD-pinned
    hipLaunchKernelGGL(feat_pack, dim3(BN_), dim3(256), 0, stream, x, Wf, bfv, h, Ap);
    hipLaunchKernelGGL(pack_wT, dim3(H_), dim3(256), 0, stream, Wnn, Qw, H_);
    hipLaunchKernelGGL(mfma_gemm, dim3(256), dim3(256), 0, stream,
                       Ap, Qw, bnn, t, KP_, H_, 0,
                       (const float*)nullptr, (const float*)nullptr, 0, stats, 2);

    for (int l = 0; l < L_; ++l) {
        const float* src1 = (l == 0) ? t : h;
        hipLaunchKernelGGL(bn_final, dim3(1), dim3(256), 0, stream,
                           stats, g1 + l * H_, b1 + l * H_, scsh);
        hipLaunchKernelGGL(bn_apply_pack, dim3(BN_ / 8), dim3(256), 0, stream,
                           src1, scsh, Ap, sqb);
        // symmetric gram -> D + chunk-min keys, XCD-pinned
        hipLaunchKernelGGL(gram_sym, dim3(1088), dim3(256), 0, stream,
                           Ap, sqb, dmat, minDp);
        hipLaunchKernelGGL(topk16, dim3(BN_ / 4), dim3(256), 0, stream,
                           dmat, minDp, idxb);
        // fused u|v gemm (N=512), XCD-pinned
        hipLaunchKernelGGL(pack_qcat, dim3(512), dim3(256), 0, stream,
                           We + (size_t)l * 2 * H_ * H_, be + (size_t)l * H_, Qw, bcat);
        hipLaunchKernelGGL(mfma_gemm, dim3(512), dim3(256), 0, stream,
                           Ap, Qw, bcat, uv, KP_, 512, 0,
                           (const float*)nullptr, (const float*)nullptr, 0,
                           (double*)nullptr, 4);
        hipLaunchKernelGGL(gather_max, dim3(512), dim3(256), 0, stream,
                           uv, idxb, t, stats);
        // BN2 + Wl with fused residual: h = h + alpha[l]*(xb@Wl + bl) (+h-stats)
        hipLaunchKernelGGL(bn_final, dim3(1), dim3(256), 0, stream,
                           stats, g2 + l * H_, b2 + l * H_, scsh);
        hipLaunchKernelGGL(bn_apply_pack, dim3(BN_ / 8), dim3(256), 0, stream,
                           t, scsh, Ap, (float*)nullptr);
        hipLaunchKernelGGL(pack_wT, dim3(H_), dim3(256), 0, stream,
                           Wl + (size_t)l * H_ * H_, Qw, H_);
        hipLaunchKernelGGL(mfma_gemm, dim3(256), dim3(256), 0, stream,
                           Ap, Qw, bl + (size_t)l * H_, h, KP_, H_, 2,
                           h, alpha, l, stats, 2);
    }

    // head
    hipLaunchKernelGGL(bn_final, dim3(1), dim3(256), 0, stream, stats, gg, bgb, scsh);
    hipLaunchKernelGGL(bn_apply_pack, dim3(BN_ / 8), dim3(256), 0, stream,
                       h, scsh, Ap, (float*)nullptr);
    hipLaunchKernelGGL(pack_wT, dim3(G_), dim3(256), 0, stream, Wg, Qw, G_);
    hipLaunchKernelGGL(mfma_gemm, dim3(512), dim3(256), 0, stream,
                       Ap, Qw, bg2, y, KP_, G_, 0,
                       (const float*)nullptr, (const float*)nullptr, 0,
                       (double*)nullptr, 4);
    hipLaunchKernelGGL(maxpool1, dim3(8, 2, 16), dim3(256), 0, stream, y, pmax);
    hipLaunchKernelGGL(maxpool2, dim3(8, 2), dim3(256), 0, stream, pmax, p0);
    hipLaunchKernelGGL(head_gemm, dim3(8, 4), dim3(256), 0, stream, p0, Wm1, bm1, p1, G_, M0_, 1);
    hipLaunchKernelGGL(head_gemm, dim3(8, 2), dim3(256), 0, stream, p1, Wm2, bm2, p2, M0_, M1_, 1);
    hipLaunchKernelGGL(head_gemm, dim3(8, 2), dim3(256), 0, stream, p2, Wm3, bm3, outp, M1_, C_, 0);
}

// Round 3
// 1100.149 us; speedup vs baseline: 1.2640x; 1.1210x over previous
//
#include <hip/hip_runtime.h>
#include <cfloat>

#define B_  8
#define N_  2048
#define H_  256
#define L_  4
#define K_  16
#define G_  512
#define M0_ 256
#define M1_ 128
#define C_  128
#define BN_ 16384   // B_*N_
#define KP_ 768     // packed split-bf16 K (3*H_)

typedef unsigned short ushort_t;
typedef __attribute__((ext_vector_type(8))) short short8;
typedef __attribute__((ext_vector_type(4))) float f32x4;

// ---------------- workspace layout (bytes) ----------------
#define OFF_H     ((size_t)0)            // 16 MB  h (fp32, persistent)
#define OFF_APACK ((size_t)16777216)     // 25.2 MB  P-pack [hi,lo,hi] (Q read via seg remap)
// free gap 41943040..67108864 hosts persistent weight packs + stats arena:
#define OFF_WPK   ((size_t)46137344)     // 5.9 MB  all weight packs (3840 rows x 768 bf16)
#define OFF_BCA   ((size_t)52035584)     // 8 KB    bcat arena (4 x 512 f32)
#define OFF_STA   ((size_t)52043776)     // 36 KB   stats arena (9 slots x 512 doubles)
#define OFF_SQ    ((size_t)67108864)     // 64 KB
#define OFF_IDX   ((size_t)67174400)     // 1 MB
#define OFF_P0    ((size_t)68231168)     // 16 KB
#define OFF_D     ((size_t)69206016)     // 134.2 MB dmat; overlays below (stream-ordered safe)
#define OFF_T     (OFF_D + (size_t)0)           // 16 MB (alive gather_max -> bn2; dmat dead)
#define OFF_UV    (OFF_D + (size_t)50331648)    // 33.5 MB (alive uv gemm -> gather); also y
#define OFF_PMAX  (OFF_D + (size_t)84672512)    // 256 KB
#define WS_NEEDED ((size_t)203423744)

// weight-pack arena row offsets
#define WPK_WNN   0
#define WPK_WL    256      // + l*256
#define WPK_WG    1280
#define WPK_QCAT  1792     // + l*512

// ---------------- helpers ----------------
static __device__ __forceinline__ ushort_t f2bf(float f) {
    unsigned u = __float_as_uint(f);
    unsigned r = (u + 0x7fffu + ((u >> 16) & 1u)) >> 16;   // RNE
    return (ushort_t)r;
}
static __device__ __forceinline__ float bf2f(ushort_t h) {
    return __uint_as_float(((unsigned)h) << 16);
}
// P-pack layout per row: [hi(0:256), lo(256:512), hi(512:768)]
static __device__ __forceinline__ void pack3(float v, ushort_t* A, size_t base, int f) {
    ushort_t hi = f2bf(v);
    ushort_t lo = f2bf(v - bf2f(hi));
    A[base + f] = hi; A[base + H_ + f] = lo; A[base + 2 * H_ + f] = hi;
}

// ---------------- kernels ----------------

// h = x @ Wf + bf ; also pack h into Apack
__global__ void feat_pack(const float* __restrict__ x, const float* __restrict__ Wf,
                          const float* __restrict__ bfv, float* __restrict__ h,
                          ushort_t* __restrict__ Ap) {
    int pt = blockIdx.x;
    int f  = threadIdx.x;
    float x0 = x[pt * 3 + 0], x1 = x[pt * 3 + 1], x2 = x[pt * 3 + 2];
    float v = x0 * Wf[f] + x1 * Wf[H_ + f] + x2 * Wf[2 * H_ + f] + bfv[f];
    h[(size_t)pt * H_ + f] = v;
    pack3(v, Ap, (size_t)pt * KP_, f);
}

// One-shot pack of ALL static weights into the persistent arena.
// rows 0..255: Wnn^T | 256..1279: Wl[l]^T | 1280..1791: Wg^T |
// rows 1792..3839: qcat[l] (rows n<256 = (We_a-We_b)^T, n>=256 = We_b^T) + bcat.
// Q-side pack layout per row: [hi, hi, lo].
__global__ void pack_all(const float* __restrict__ Wnn, const float* __restrict__ Wl,
                         const float* __restrict__ Wg, const float* __restrict__ We,
                         const float* __restrict__ be, ushort_t* __restrict__ Qp,
                         float* __restrict__ bcat) {
    int row = blockIdx.x, k = threadIdx.x;
    float w;
    if (row < 1792) {
        const float* W; int Nd, n;
        if (row < 256)        { W = Wnn; Nd = 256; n = row; }
        else if (row < 1280)  { int l = (row - 256) >> 8;
                                W = Wl + (size_t)l * (H_ * H_); Nd = 256; n = (row - 256) & 255; }
        else                  { W = Wg; Nd = 512; n = row - 1280; }
        w = W[(size_t)k * Nd + n];
    } else {
        int rr = row - 1792; int l = rr >> 9; int n = rr & 511;
        const float* We_l = We + (size_t)l * 2 * H_ * H_;
        if (n < H_) w = We_l[(size_t)k * H_ + n] - We_l[(size_t)H_ * H_ + (size_t)k * H_ + n];
        else        w = We_l[(size_t)H_ * H_ + (size_t)k * H_ + (n - H_)];
        if (k == 0) bcat[l * 512 + n] = (n < H_) ? be[l * H_ + n] : 0.f;
    }
    ushort_t hi = f2bf(w), lo = f2bf(w - bf2f(hi));
    size_t base = (size_t)row * KP_;
    Qp[base + k] = hi; Qp[base + H_ + k] = hi; Qp[base + 2 * H_ + k] = lo;
}

// ---- split-bf16 MFMA GEMM: out = P (M x K) . Q^T (N x K) ----
// mode 0: out[r][c] = acc + aux[c]
// mode 2: out[r][c] = resid[r][c] + alphap[aidx]*(acc+aux[c])
// stats != nullptr: accumulate per-column sum/sumsq of written values (BN prestats)
// nx != 0: 1-D grid of nx*128 blocks, XCD-pinned: z=blk&7 owns M-rows of batch z.
__global__ __launch_bounds__(256) void mfma_gemm(
    const ushort_t* __restrict__ P, const ushort_t* __restrict__ Q,
    const float* __restrict__ aux, float* __restrict__ out,
    int Kd, int ldOut, int mode, const float* __restrict__ resid,
    const float* __restrict__ alphap, int aidx, double* __restrict__ stats,
    int nx) {
    __shared__ __align__(16) ushort_t As[128 * 32];
    __shared__ __align__(16) ushort_t Bs[128 * 32];
    __shared__ float cs1[4][64], cs2[4][64];
    int i0, j0;
    if (nx) {
        int blk = blockIdx.x;
        int z = blk & 7;
        int rest = blk >> 3;
        int xb = rest % nx;
        int ys = rest / nx;            // 0..15
        i0 = (z * 16 + ys) * 128;
        j0 = xb * 128;
    } else {
        i0 = blockIdx.y * 128; j0 = blockIdx.x * 128;
    }
    int tid = threadIdx.x;
    int lane = tid & 63, wave = tid >> 6;
    int wm = wave & 1, wn = wave >> 1;
    int m16 = lane & 15, kq = (lane >> 4) * 8;

    f32x4 acc[4][4];
    f32x4 zero = {0.f, 0.f, 0.f, 0.f};
#pragma unroll
    for (int i = 0; i < 4; ++i)
#pragma unroll
        for (int j = 0; j < 4; ++j) acc[i][j] = zero;

    int srow = tid >> 2;
    int skc  = (tid & 3) * 8;

    for (int k0 = 0; k0 < Kd; k0 += 32) {
#pragma unroll
        for (int s = 0; s < 2; ++s) {
            int row = srow + s * 64;
            const ushort_t* gpA = P + (size_t)(i0 + row) * Kd + k0 + skc;
            const ushort_t* gpB = Q + (size_t)(j0 + row) * Kd + k0 + skc;
            __builtin_amdgcn_global_load_lds(
                (const __attribute__((address_space(1))) void*)gpA,
                (__attribute__((address_space(3))) void*)(As + (size_t)(wave * 64 + s * 256) * 8),
                16, 0, 0);
            __builtin_amdgcn_global_load_lds(
                (const __attribute__((address_space(1))) void*)gpB,
                (__attribute__((address_space(3))) void*)(Bs + (size_t)(wave * 64 + s * 256) * 8),
                16, 0, 0);
        }
        __syncthreads();
        short8 af[4], bfr[4];
#pragma unroll
        for (int fi = 0; fi < 4; ++fi)
            af[fi] = *(const short8*)(As + (wm * 64 + fi * 16 + m16) * 32 + kq);
#pragma unroll
        for (int fj = 0; fj < 4; ++fj)
            bfr[fj] = *(const short8*)(Bs + (wn * 64 + fj * 16 + m16) * 32 + kq);
#pragma unroll
        for (int fi = 0; fi < 4; ++fi)
#pragma unroll
            for (int fj = 0; fj < 4; ++fj)
                acc[fi][fj] = __builtin_amdgcn_mfma_f32_16x16x32_bf16(
                    af[fi], bfr[fj], acc[fi][fj], 0, 0, 0);
        __syncthreads();
    }
    float alpha = (mode == 2) ? alphap[aidx] : 0.f;
    int rbase = i0 + wm * 64 + (lane >> 4) * 4;
    int cbase = j0 + wn * 64 + m16;
    float s1[4] = {0.f, 0.f, 0.f, 0.f}, s2[4] = {0.f, 0.f, 0.f, 0.f};
#pragma unroll
    for (int fi = 0; fi < 4; ++fi) {
#pragma unroll
        for (int fj = 0; fj < 4; ++fj) {
            int c = cbase + fj * 16;
            float a = aux[c];
#pragma unroll
            for (int r = 0; r < 4; ++r) {
                int gr = rbase + fi * 16 + r;
                size_t oidx = (size_t)gr * ldOut + c;
                float val;
                if (mode == 2) val = resid[oidx] + alpha * (acc[fi][fj][r] + a);
                else           val = acc[fi][fj][r] + a;
                out[oidx] = val;
                s1[fj] += val; s2[fj] += val * val;
            }
        }
    }
    if (stats) {
#pragma unroll
        for (int fj = 0; fj < 4; ++fj) {
            float a1 = s1[fj], a2 = s2[fj];
            a1 += __shfl_xor(a1, 16); a1 += __shfl_xor(a1, 32);
            a2 += __shfl_xor(a2, 16); a2 += __shfl_xor(a2, 32);
            if ((lane >> 4) == 0) {
                cs1[wave][fj * 16 + m16] = a1;
                cs2[wave][fj * 16 + m16] = a2;
            }
        }
        __syncthreads();
        if (tid < 128) {
            int wnl = tid >> 6, cl = tid & 63;
            float t1 = cs1[2 * wnl][cl] + cs1[2 * wnl + 1][cl];
            float t2 = cs2[2 * wnl][cl] + cs2[2 * wnl + 1][cl];
            int c = j0 + tid;
            atomicAdd(&stats[c], (double)t1);
            atomicAdd(&stats[H_ + c], (double)t2);
        }
    }
}

// ---- symmetric gram: D[i][j] = sq[j] - 2 <x_i, x_j>, upper-tri tile pairs only ----
// 1-D grid 1088: z = blk&7 (XCD pin), p = blk>>3 enumerates bi<=bj tile pairs.
// B-side reads P-pack with segment remap (0,2,1).
// Epilogue: wave-private LDS transpose (separate array; VGPR 84, measured best)
// -> all stores f32x4 NT with contiguous 64B runs per row.
__global__ __launch_bounds__(256) void gram_sym(const ushort_t* __restrict__ Ap,
                                                const float* __restrict__ sqb,
                                                float* __restrict__ D) {
    __shared__ __align__(16) ushort_t As[128 * 32];
    __shared__ __align__(16) ushort_t Bs[128 * 32];
    __shared__ __align__(16) float stg[4][1280];   // wave-private transpose pool
    int blk = blockIdx.x;
    int z = blk & 7;
    int p = blk >> 3;
    int bi = 0, rem = p;
    while (rem >= 16 - bi) { rem -= 16 - bi; ++bi; }
    int bj = bi + rem;
    const ushort_t* Pz = Ap + (size_t)z * N_ * KP_;
    const float* sqz = sqb + (size_t)z * N_;
    float* Dz = D + (size_t)z * N_ * N_;
    int i0 = bi * 128, j0 = bj * 128;

    int tid = threadIdx.x;
    int lane = tid & 63, wave = tid >> 6;
    int wm = wave & 1, wn = wave >> 1;
    int m16 = lane & 15, q4 = lane >> 4;
    int kq = q4 * 8;

    f32x4 acc[4][4];
    f32x4 zero = {0.f, 0.f, 0.f, 0.f};
#pragma unroll
    for (int i = 0; i < 4; ++i)
#pragma unroll
        for (int j = 0; j < 4; ++j) acc[i][j] = zero;

    int srow = tid >> 2;
    int skc  = (tid & 3) * 8;

    for (int k0 = 0; k0 < KP_; k0 += 32) {
        // Q segment remap: seg0->seg0(hi), seg1->seg2(hi), seg2->seg1(lo)
        int kb = (k0 < 256) ? k0 : ((k0 < 512) ? k0 + 256 : k0 - 256);
#pragma unroll
        for (int s = 0; s < 2; ++s) {
            int row = srow + s * 64;
            const ushort_t* gpA = Pz + (size_t)(i0 + row) * KP_ + k0 + skc;
            const ushort_t* gpB = Pz + (size_t)(j0 + row) * KP_ + kb + skc;
            __builtin_amdgcn_global_load_lds(
                (const __attribute__((address_space(1))) void*)gpA,
                (__attribute__((address_space(3))) void*)(As + (size_t)(wave * 64 + s * 256) * 8),
                16, 0, 0);
            __builtin_amdgcn_global_load_lds(
                (const __attribute__((address_space(1))) void*)gpB,
                (__attribute__((address_space(3))) void*)(Bs + (size_t)(wave * 64 + s * 256) * 8),
                16, 0, 0);
        }
        __syncthreads();
        short8 af[4], bfr[4];
#pragma unroll
        for (int fi = 0; fi < 4; ++fi)
            af[fi] = *(const short8*)(As + (wm * 64 + fi * 16 + m16) * 32 + kq);
#pragma unroll
        for (int fj = 0; fj < 4; ++fj)
            bfr[fj] = *(const short8*)(Bs + (wn * 64 + fj * 16 + m16) * 32 + kq);
#pragma unroll
        for (int fi = 0; fi < 4; ++fi)
#pragma unroll
            for (int fj = 0; fj < 4; ++fj)
                acc[fi][fj] = __builtin_amdgcn_mfma_f32_16x16x32_bf16(
                    af[fi], bfr[fj], acc[fi][fj], 0, 0, 0);
        __syncthreads();
    }

    float* sg = stg[wave];
    float scl[4];
#pragma unroll
    for (int fj = 0; fj < 4; ++fj) scl[fj] = sqz[j0 + wn * 64 + fj * 16 + m16];
    float sr[4][4];
#pragma unroll
    for (int fi = 0; fi < 4; ++fi) {
        float4 s4 = *(const float4*)(sqz + i0 + wm * 64 + fi * 16 + q4 * 4);
        sr[fi][0] = s4.x; sr[fi][1] = s4.y; sr[fi][2] = s4.z; sr[fi][3] = s4.w;
    }

    // normal orientation: per fi, wave-private [16][68] transpose -> f32x4 stores
    int rr = lane >> 2, cc = lane & 3;
#pragma unroll
    for (int fi = 0; fi < 4; ++fi) {
#pragma unroll
        for (int fj = 0; fj < 4; ++fj)
#pragma unroll
            for (int r = 0; r < 4; ++r)
                sg[(q4 * 4 + r) * 68 + fj * 16 + m16] = scl[fj] - 2.f * acc[fi][fj][r];
        float* drow = Dz + (size_t)(i0 + wm * 64 + fi * 16 + rr) * N_ + j0 + wn * 64;
#pragma unroll
        for (int t = 0; t < 4; ++t) {
            int chunk = cc + 4 * t;
            f32x4 o = *(const f32x4*)(sg + rr * 68 + chunk * 4);
            __builtin_nontemporal_store(o, (f32x4*)(drow + chunk * 4));
        }
    }

    // transposed orientation (off-diag): per fi, wave-private [64][20] -> f32x4 stores
    if (bi != bj) {
#pragma unroll
        for (int fi = 0; fi < 4; ++fi) {
#pragma unroll
            for (int fj = 0; fj < 4; ++fj)
#pragma unroll
                for (int r = 0; r < 4; ++r)
                    sg[(fj * 16 + m16) * 20 + q4 * 4 + r] =
                        sr[fi][r] - 2.f * acc[fi][fj][r];
            int chunk = lane & 3;
#pragma unroll
            for (int u = 0; u < 4; ++u) {
                int cr = (lane >> 2) + 16 * u;
                f32x4 o = *(const f32x4*)(sg + cr * 20 + chunk * 4);
                __builtin_nontemporal_store(o,
                    (f32x4*)(Dz + (size_t)(j0 + wn * 64 + cr) * N_ +
                             i0 + wm * 64 + fi * 16 + chunk * 4));
            }
        }
    }
}

// ---- threshold top-16 smallest per row (exact, lex (value,col) tie-break) ----
__global__ __launch_bounds__(256) void topk16(const float* __restrict__ D,
                                              int* __restrict__ idxb) {
    __shared__ unsigned long long cand[4][256];
    __shared__ int cnt[4];
    int w = threadIdx.x >> 6, lane = threadIdx.x & 63;
    int row = blockIdx.x * 4 + w;
    const float* dp = D + (size_t)row * N_;
    unsigned sk[32];
#pragma unroll
    for (int t = 0; t < 8; ++t) {
        f32x4 v4 = __builtin_nontemporal_load((const f32x4*)(dp + t * 256 + lane * 4));
#pragma unroll
        for (int j = 0; j < 4; ++j) {
            unsigned u = __float_as_uint(v4[j]);
            sk[t * 4 + j] = (u & 0x80000000u) ? ~u : (u | 0x80000000u);
        }
    }
    if (lane == 0) cnt[w] = 0;
    unsigned vm = sk[0];
#pragma unroll
    for (int i = 1; i < 32; ++i) vm = min(vm, sk[i]);
#pragma unroll
    for (int k = 2; k <= 64; k <<= 1) {
#pragma unroll
        for (int j = k >> 1; j > 0; j >>= 1) {
            unsigned pv = __shfl_xor(vm, j);
            bool up = ((lane & k) == 0);
            bool lower = ((lane & j) == 0);
            unsigned mn = min(vm, pv), mx = max(vm, pv);
            vm = (lower == up) ? mn : mx;
        }
    }
    unsigned T = __shfl(vm, 15);   // 16th smallest lane-min >= 16th order statistic
    __syncthreads();
#pragma unroll
    for (int i = 0; i < 32; ++i) {
        if (sk[i] <= T) {
            unsigned col = (unsigned)((i >> 2) * 256 + lane * 4 + (i & 3));
            int s = atomicAdd(&cnt[w], 1);
            if (s < 256) cand[w][s] = ((unsigned long long)sk[i] << 32) | col;
        }
    }
    __syncthreads();
    int cn = cnt[w];
    if (cn <= 64) {
        unsigned long long mykey = (lane < cn) ? cand[w][lane] : ~0ull;
        for (int it = 0; it < 16; ++it) {
            unsigned long long best = mykey;
#pragma unroll
            for (int off = 32; off; off >>= 1) {
                unsigned long long o = __shfl_xor(best, off);
                if (o < best) best = o;
            }
            if (mykey == best) mykey = ~0ull;
            if (lane == 0) idxb[row * 16 + it] = (int)(unsigned)(best & 0xffffffffu);
        }
    } else if (cn <= 256) {
        for (int it = 0; it < 16; ++it) {
            unsigned long long best = ~0ull;
            for (int i = lane; i < cn; i += 64) {
                unsigned long long c = cand[w][i];
                if (c < best) best = c;
            }
#pragma unroll
            for (int off = 32; off; off >>= 1) {
                unsigned long long o = __shfl_xor(best, off);
                if (o < best) best = o;
            }
            for (int i = lane; i < cn; i += 64)
                if (cand[w][i] == best) cand[w][i] = ~0ull;
            if (lane == 0) idxb[row * 16 + it] = (int)(unsigned)(best & 0xffffffffu);
        }
    } else {
        unsigned mask = 0;
        for (int it = 0; it < 16; ++it) {
            unsigned long long key = ~0ull;
#pragma unroll
            for (int i = 0; i < 32; ++i) {
                if (!((mask >> i) & 1u)) {
                    unsigned long long k2 = ((unsigned long long)sk[i] << 32) |
                        (unsigned)((i >> 2) * 256 + lane * 4 + (i & 3));
                    if (k2 < key) key = k2;
                }
            }
#pragma unroll
            for (int off = 32; off; off >>= 1) {
                unsigned long long o = __shfl_xor(key, off);
                if (o < key) key = o;
            }
            unsigned jc = (unsigned)(key & 0xffffffffu);
            int li = ((jc & 255) >> 2);
            int ii = ((jc >> 8) << 2) | (jc & 3);
            if (lane == li) mask |= 1u << ii;
            if (lane == 0) idxb[row * 16 + it] = (int)jc;
        }
    }
}

// t[b,i,h] = uv[row][h] + max_k uv[(b,idx_k)][256+h]; accumulates BN stats of t.
// XCD-pinned: z = blk&7 -> each XCD gathers within its own batch's 2 MB v-half.
__global__ void gather_max(const float* __restrict__ uv, const int* __restrict__ idxb,
                           float* __restrict__ outp, double* __restrict__ stats) {
    int blk = blockIdx.x;
    int b = blk & 7;
    int strip = blk >> 3;               // 0..63
    int r0 = b * N_ + strip * 32;
    int f = threadIdx.x;
    float s1 = 0.f, s2 = 0.f;
    for (int rr = 0; rr < 32; ++rr) {
        int row = r0 + rr;
        const int* ip = idxb + row * 16;
        float m = -FLT_MAX;
#pragma unroll
        for (int k = 0; k < 16; ++k) {
            int j = ip[k];
            m = fmaxf(m, uv[((size_t)((b << 11) + j)) * 512 + 256 + f]);
        }
        float v = uv[(size_t)row * 512 + f] + m;
        outp[(size_t)row * H_ + f] = v;
        s1 += v; s2 += v * v;
    }
    atomicAdd(&stats[f], (double)s1);
    atomicAdd(&stats[H_ + f], (double)s2);
}

// ---- batchnorm helpers ----
// zero the 9-slot stats arena (grid 9 x 512 threads)
__global__ void bn_zero(double* s) { s[(size_t)blockIdx.x * 512 + threadIdx.x] = 0.0; }

// BN+ReLU fused with split-bf16 packing and (optional) row sqnorm reduce.
// scale/shift computed IN-BLOCK from the stats slot (bitwise-identical to the
// former bn_final kernel). Vectorized: one wave = 2 rows, lane owns 8 features.
__global__ void bn_apply_pack(const float* __restrict__ X, const double* __restrict__ sums,
                              const float* __restrict__ g, const float* __restrict__ b,
                              ushort_t* __restrict__ Ap, float* __restrict__ sq) {
    __shared__ float scsh[512];
    int tid = threadIdx.x;
    {
        double m  = sums[tid] / (double)BN_;
        double var = sums[H_ + tid] / (double)BN_ - m * m;
        double inv = 1.0 / sqrt(var + 1e-5);
        float sc = g[tid] * (float)inv;
        scsh[tid] = sc;
        scsh[H_ + tid] = b[tid] - (float)m * sc;
    }
    __syncthreads();
    int row = blockIdx.x * 8 + (tid >> 5);
    int f0  = (tid & 31) * 8;
    const float* xp = X + (size_t)row * H_ + f0;
    f32x4 x0 = *(const f32x4*)(xp);
    f32x4 x1 = *(const f32x4*)(xp + 4);
    f32x4 sc0 = *(const f32x4*)(scsh + f0);
    f32x4 sc1 = *(const f32x4*)(scsh + f0 + 4);
    f32x4 sh0 = *(const f32x4*)(scsh + H_ + f0);
    f32x4 sh1 = *(const f32x4*)(scsh + H_ + f0 + 4);
    float v[8];
#pragma unroll
    for (int i = 0; i < 4; ++i) {
        v[i]     = fmaxf(x0[i] * sc0[i] + sh0[i], 0.f);
        v[i + 4] = fmaxf(x1[i] * sc1[i] + sh1[i], 0.f);
    }
    short8 hi8, lo8;
#pragma unroll
    for (int i = 0; i < 8; ++i) {
        ushort_t hi = f2bf(v[i]);
        ushort_t lo = f2bf(v[i] - bf2f(hi));
        hi8[i] = (short)hi; lo8[i] = (short)lo;
    }
    ushort_t* ap = Ap + (size_t)row * KP_ + f0;
    *(short8*)(ap)            = hi8;
    *(short8*)(ap + H_)       = lo8;
    *(short8*)(ap + 2 * H_)   = hi8;
    if (sq) {
        float s = 0.f;
#pragma unroll
        for (int i = 0; i < 8; ++i) s += v[i] * v[i];
#pragma unroll
        for (int off = 16; off; off >>= 1) s += __shfl_down(s, off, 32);
        if ((tid & 31) == 0) sq[row] = s;
    }
}

__global__ void maxpool1(const float* __restrict__ y, float* __restrict__ pmax) {
    int b = blockIdx.x, gc = blockIdx.y, nc = blockIdx.z;
    int g = gc * 256 + threadIdx.x;
    const float* yb = y + ((size_t)b * N_ + (size_t)nc * 128) * G_;
    float m = -FLT_MAX;
    for (int n = 0; n < 128; ++n) m = fmaxf(m, yb[(size_t)n * G_ + g]);
    pmax[((size_t)(b * 16 + nc)) * G_ + g] = m;
}

__global__ void maxpool2(const float* __restrict__ pmax, float* __restrict__ p) {
    int b = blockIdx.x;
    int g = blockIdx.y * 256 + threadIdx.x;
    float m = -FLT_MAX;
    for (int c = 0; c < 16; ++c) m = fmaxf(m, pmax[((size_t)(b * 16 + c)) * G_ + g]);
    p[(size_t)b * G_ + g] = m;
}

// fused MLP head: p1=relu(p0@Wm1+bm1); p2=relu(p1@Wm2+bm2); out=p2@Wm3+bm3.
// One block per batch row; each stage replicates head_gemm's exact 4-way K-split
// and red[0]+red[1]+red[2]+red[3]+bias summation order (bitwise-identical).
__global__ __launch_bounds__(256) void head3(const float* __restrict__ p0,
    const float* __restrict__ Wm1, const float* __restrict__ bm1,
    const float* __restrict__ Wm2, const float* __restrict__ bm2,
    const float* __restrict__ Wm3, const float* __restrict__ bm3,
    float* __restrict__ out) {
    __shared__ float s0[512];
    __shared__ float s1[256];
    __shared__ float red[4][64];
    int b = blockIdx.x, tid = threadIdx.x;
    s0[tid] = p0[(size_t)b * 512 + tid];
    s0[256 + tid] = p0[(size_t)b * 512 + 256 + tid];
    int cl = tid & 63, ks = tid >> 6;
    __syncthreads();
    // stage 1: 256 outs, K=512 (kper=128)
    for (int cg = 0; cg < 4; ++cg) {
        int c = cg * 64 + cl;
        const float* Apt = s0 + ks * 128;
        const float* Wp  = Wm1 + (size_t)(ks * 128) * M0_ + c;
        float acc = 0.f;
        for (int k = 0; k < 128; k += 8)
#pragma unroll
            for (int u2 = 0; u2 < 8; ++u2)
                acc += Apt[k + u2] * Wp[(size_t)(k + u2) * M0_];
        red[ks][cl] = acc;
        __syncthreads();
        if (ks == 0) {
            float s = red[0][cl] + red[1][cl] + red[2][cl] + red[3][cl] + bm1[c];
            s1[c] = fmaxf(s, 0.f);
        }
        __syncthreads();
    }
    // stage 2: 128 outs, K=256 (kper=64)
    float s2v[2];
    for (int cg = 0; cg < 2; ++cg) {
        int c = cg * 64 + cl;
        const float* Apt = s1 + ks * 64;
        const float* Wp  = Wm2 + (size_t)(ks * 64) * M1_ + c;
        float acc = 0.f;
        for (int k = 0; k < 64; k += 8)
#pragma unroll
            for (int u2 = 0; u2 < 8; ++u2)
                acc += Apt[k + u2] * Wp[(size_t)(k + u2) * M1_];
        red[ks][cl] = acc;
        __syncthreads();
        s2v[cg] = 0.f;
        if (ks == 0) {
            float s = red[0][cl] + red[1][cl] + red[2][cl] + red[3][cl] + bm2[c];
            s2v[cg] = fmaxf(s, 0.f);
        }
        __syncthreads();
    }
    if (ks == 0) { s0[cl] = s2v[0]; s0[64 + cl] = s2v[1]; }
    __syncthreads();
    // stage 3: 128 outs, K=128 (kper=32)
    for (int cg = 0; cg < 2; ++cg) {
        int c = cg * 64 + cl;
        const float* Apt = s0 + ks * 32;
        const float* Wp  = Wm3 + (size_t)(ks * 32) * C_ + c;
        float acc = 0.f;
        for (int k = 0; k < 32; k += 8)
#pragma unroll
            for (int u2 = 0; u2 < 8; ++u2)
                acc += Apt[k + u2] * Wp[(size_t)(k + u2) * C_];
        red[ks][cl] = acc;
        __syncthreads();
        if (ks == 0)
            out[(size_t)b * C_ + c] =
                red[0][cl] + red[1][cl] + red[2][cl] + red[3][cl] + bm3[c];
        __syncthreads();
    }
}

// ---------------- launch ----------------
extern "C" void kernel_launch(void* const* d_in, const int* in_sizes, int n_in,
                              void* d_out, int out_size, void* d_ws, size_t ws_size,
                              hipStream_t stream) {
    (void)in_sizes; (void)n_in; (void)out_size;
    if (ws_size < WS_NEEDED) return;

    const float* x    = (const float*)d_in[0];
    const float* Wf   = (const float*)d_in[2];
    const float* bfv  = (const float*)d_in[3];
    const float* Wnn  = (const float*)d_in[4];
    const float* bnn  = (const float*)d_in[5];
    const float* g1   = (const float*)d_in[6];
    const float* b1   = (const float*)d_in[7];
    const float* We   = (const float*)d_in[8];
    const float* be   = (const float*)d_in[9];
    const float* g2   = (const float*)d_in[10];
    const float* b2   = (const float*)d_in[11];
    const float* Wl   = (const float*)d_in[12];
    const float* bl   = (const float*)d_in[13];
    const float* alpha= (const float*)d_in[14];
    const float* gg   = (const float*)d_in[15];
    const float* bgb  = (const float*)d_in[16];
    const float* Wg   = (const float*)d_in[17];
    const float* bg2  = (const float*)d_in[18];
    const float* Wm1  = (const float*)d_in[19];
    const float* bm1  = (const float*)d_in[20];
    const float* Wm2  = (const float*)d_in[21];
    const float* bm2  = (const float*)d_in[22];
    const float* Wm3  = (const float*)d_in[23];
    const float* bm3  = (const float*)d_in[24];
    float* outp = (float*)d_out;

    char* ws = (char*)d_ws;
    float*    h    = (float*)(ws + OFF_H);
    ushort_t* Ap   = (ushort_t*)(ws + OFF_APACK);
    ushort_t* Qpk  = (ushort_t*)(ws + OFF_WPK);
    float*    bcatA= (float*)(ws + OFF_BCA);
    double*   sta  = (double*)(ws + OFF_STA);
    float*    sqb  = (float*)(ws + OFF_SQ);
    int*      idxb = (int*)  (ws + OFF_IDX);
    float*    p0   = (float*)(ws + OFF_P0);
    float*    dmat = (float*)(ws + OFF_D);
    float*    t    = (float*)(ws + OFF_T);
    float*    uv   = (float*)(ws + OFF_UV);
    float*    y    = (float*)(ws + OFF_UV);
    float*    pmax = (float*)(ws + OFF_PMAX);

    ushort_t* Qwnn = Qpk + (size_t)WPK_WNN * KP_;
    ushort_t* Qwg  = Qpk + (size_t)WPK_WG  * KP_;

    // one-time zero of the 9-slot stats arena; pack all static weights once
    hipLaunchKernelGGL(bn_zero, dim3(9), dim3(512), 0, stream, sta);
    hipLaunchKernelGGL(pack_all, dim3(3840), dim3(256), 0, stream,
                       Wnn, Wl, Wg, We, be, Qpk, bcatA);

    // h = x@Wf+bf (+pack), t = h@Wnn+bnn via MFMA (t-stats -> slot 0), XCD-pinned
    hipLaunchKernelGGL(feat_pack, dim3(BN_), dim3(256), 0, stream, x, Wf, bfv, h, Ap);
    hipLaunchKernelGGL(mfma_gemm, dim3(256), dim3(256), 0, stream,
                       Ap, Qwnn, bnn, t, KP_, H_, 0,
                       (const float*)nullptr, (const float*)nullptr, 0, sta, 2);

    for (int l = 0; l < L_; ++l) {
        const float* src1 = (l == 0) ? t : h;
        // BN1 from slot 2l (inlined scale/shift), pack + row sqnorms
        hipLaunchKernelGGL(bn_apply_pack, dim3(BN_ / 8), dim3(256), 0, stream,
                           src1, sta + (size_t)(2 * l) * 512,
                           g1 + l * H_, b1 + l * H_, Ap, sqb);
        // symmetric gram -> D (both triangles written, upper computed), XCD-pinned
        hipLaunchKernelGGL(gram_sym, dim3(1088), dim3(256), 0, stream,
                           Ap, sqb, dmat);
        hipLaunchKernelGGL(topk16, dim3(BN_ / 4), dim3(256), 0, stream, dmat, idxb);
        // fused u|v gemm (N=512), XCD-pinned, pre-packed qcat
        hipLaunchKernelGGL(mfma_gemm, dim3(512), dim3(256), 0, stream,
                           Ap, Qpk + (size_t)(WPK_QCAT + l * 512) * KP_,
                           bcatA + (size_t)l * 512, uv, KP_, 512, 0,
                           (const float*)nullptr, (const float*)nullptr, 0,
                           (double*)nullptr, 4);
        // gather+max (t-stats -> slot 2l+1)
        hipLaunchKernelGGL(gather_max, dim3(512), dim3(256), 0, stream,
                           uv, idxb, t, sta + (size_t)(2 * l + 1) * 512);
        // BN2 from slot 2l+1, pack
        hipLaunchKernelGGL(bn_apply_pack, dim3(BN_ / 8), dim3(256), 0, stream,
                           t, sta + (size_t)(2 * l + 1) * 512,
                           g2 + l * H_, b2 + l * H_, Ap, (float*)nullptr);
        // Wl gemm with fused residual: h = h + alpha[l]*(xb@Wl + bl) (h-stats -> slot 2l+2)
        hipLaunchKernelGGL(mfma_gemm, dim3(256), dim3(256), 0, stream,
                           Ap, Qpk + (size_t)(WPK_WL + l * 256) * KP_,
                           bl + (size_t)l * H_, h, KP_, H_, 2,
                           h, alpha, l, sta + (size_t)(2 * l + 2) * 512, 2);
    }

    // head: BN from slot 8, pack, y = xb@Wg+bg2, pools, fused MLP
    hipLaunchKernelGGL(bn_apply_pack, dim3(BN_ / 8), dim3(256), 0, stream,
                       h, sta + (size_t)8 * 512, gg, bgb, Ap, (float*)nullptr);
    hipLaunchKernelGGL(mfma_gemm, dim3(512), dim3(256), 0, stream,
                       Ap, Qwg, bg2, y, KP_, G_, 0,
                       (const float*)nullptr, (const float*)nullptr, 0,
                       (double*)nullptr, 4);
    hipLaunchKernelGGL(maxpool1, dim3(8, 2, 16), dim3(256), 0, stream, y, pmax);
    hipLaunchKernelGGL(maxpool2, dim3(8, 2), dim3(256), 0, stream, pmax, p0);
    hipLaunchKernelGGL(head3, dim3(8), dim3(256), 0, stream,
                       p0, Wm1, bm1, Wm2, bm2, Wm3, bm3, outp);
}

// Round 4
// 1047.976 us; speedup vs baseline: 1.3269x; 1.0498x over previous
//
#include <hip/hip_runtime.h>
#include <cfloat>

#define B_  8
#define N_  2048
#define H_  256
#define L_  4
#define K_  16
#define G_  512
#define M0_ 256
#define M1_ 128
#define C_  128
#define BN_ 16384   // B_*N_
#define KP_ 768     // effective split-bf16 K (3*H_)
#define KPC_ 512    // compact pack row stride [hi(0:256) | lo(256:512)]

typedef unsigned short ushort_t;
typedef __attribute__((ext_vector_type(8))) short short8;
typedef __attribute__((ext_vector_type(4))) float f32x4;

// ---------------- workspace layout (bytes) ----------------
// shared fixed region
#define OFF_H     ((size_t)0)            // 16 MB   h (fp32, persistent)
#define OFF_APACK ((size_t)16777216)     // 16.8 MB compact P-pack [hi|lo]
#define OFF_WPK   ((size_t)33554432)     // 3.93 MB all weight packs (3840 x 512 bf16)
#define OFF_BCA   ((size_t)37486592)     // 8 KB    bcat arena
#define OFF_STA   ((size_t)37494784)     // 36 KB   stats arena (9 x 512 doubles)
#define OFF_SQ    ((size_t)37531648)     // 64 KB
#define OFF_IDX   ((size_t)37597184)     // 1 MB -> ends 38,645,760
// big path: uv gets its own home (so it can be written concurrently with D)
#define OFF_UVBIG ((size_t)38645760)     // 33.5 MB -> ends 72,200,192
#define OFF_DSML  ((size_t)69206016)     // small path D (uv/t/pmax overlay inside)
#define OFF_DBIG  ((size_t)72200192)     // big path D
#define WS_SMALL  ((size_t)203423744)    // OFF_DSML + 134,217,728
#define WS_BIG    ((size_t)206417920)    // OFF_DBIG + 134,217,728

// weight-pack arena row offsets
#define WPK_WNN   0
#define WPK_WL    256      // + l*256
#define WPK_WG    1280
#define WPK_QCAT  1792     // + l*512

// ---------------- helpers ----------------
static __device__ __forceinline__ ushort_t f2bf(float f) {
    unsigned u = __float_as_uint(f);
    unsigned r = (u + 0x7fffu + ((u >> 16) & 1u)) >> 16;   // RNE
    return (ushort_t)r;
}
static __device__ __forceinline__ float bf2f(ushort_t h) {
    return __uint_as_float(((unsigned)h) << 16);
}
// segment remaps on the compact [hi|lo] pack.
// A-side effective order [hi,lo,hi]; B-side effective order [hi,hi,lo].
static __device__ __forceinline__ int kmapA(int k0) { return (k0 < KPC_) ? k0 : k0 - KPC_; }
static __device__ __forceinline__ int kmapB(int k0) { return (k0 < 256)  ? k0 : k0 - 256; }

// ---------------- fused prep: feat_pack + pack_all + stats zero ----------------
// blocks [0,16384): h = x@Wf+bf and compact-pack into Ap
// blocks [16384,20224): pack all static weights (rows as in WPK_* map)
// blocks [20224,20233): zero the 9-slot stats arena
__global__ void prep(const float* __restrict__ x, const float* __restrict__ Wf,
                     const float* __restrict__ bfv, float* __restrict__ h,
                     ushort_t* __restrict__ Ap,
                     const float* __restrict__ Wnn, const float* __restrict__ Wl,
                     const float* __restrict__ Wg, const float* __restrict__ We,
                     const float* __restrict__ be, ushort_t* __restrict__ Qp,
                     float* __restrict__ bcat, double* __restrict__ sta) {
    int blk = blockIdx.x;
    int tid = threadIdx.x;
    if (blk < BN_) {
        int pt = blk, f = tid;
        float x0 = x[pt * 3 + 0], x1 = x[pt * 3 + 1], x2 = x[pt * 3 + 2];
        float v = x0 * Wf[f] + x1 * Wf[H_ + f] + x2 * Wf[2 * H_ + f] + bfv[f];
        h[(size_t)pt * H_ + f] = v;
        ushort_t hi = f2bf(v), lo = f2bf(v - bf2f(hi));
        size_t base = (size_t)pt * KPC_;
        Ap[base + f] = hi; Ap[base + H_ + f] = lo;
    } else if (blk < BN_ + 3840) {
        int row = blk - BN_, k = tid;
        float w;
        if (row < 1792) {
            const float* W; int Nd, n;
            if (row < 256)        { W = Wnn; Nd = 256; n = row; }
            else if (row < 1280)  { int l = (row - 256) >> 8;
                                    W = Wl + (size_t)l * (H_ * H_); Nd = 256; n = (row - 256) & 255; }
            else                  { W = Wg; Nd = 512; n = row - 1280; }
            w = W[(size_t)k * Nd + n];
        } else {
            int rr = row - 1792; int l = rr >> 9; int n = rr & 511;
            const float* We_l = We + (size_t)l * 2 * H_ * H_;
            if (n < H_) w = We_l[(size_t)k * H_ + n] - We_l[(size_t)H_ * H_ + (size_t)k * H_ + n];
            else        w = We_l[(size_t)H_ * H_ + (size_t)k * H_ + (n - H_)];
            if (k == 0) bcat[l * 512 + n] = (n < H_) ? be[l * H_ + n] : 0.f;
        }
        ushort_t hi = f2bf(w), lo = f2bf(w - bf2f(hi));
        size_t base = (size_t)row * KPC_;
        Qp[base + k] = hi; Qp[base + H_ + k] = lo;
    } else {
        int slot = blk - (BN_ + 3840);
        sta[(size_t)slot * 512 + tid] = 0.0;
        sta[(size_t)slot * 512 + 256 + tid] = 0.0;
    }
}

// ---- split-bf16 MFMA GEMM core (compact packs, K=768 via remaps) ----
// mode 0: out[r][c] = acc + aux[c]
// mode 2: out[r][c] = resid[r][c] + alphap[aidx]*(acc+aux[c])
// stats != nullptr: accumulate per-column sum/sumsq of written values
// nx != 0: 1-D grid of nx*128 blocks, XCD-pinned: z=blk&7 owns batch z's rows.
__global__ __launch_bounds__(256) void mfma_gemm(
    const ushort_t* __restrict__ P, const ushort_t* __restrict__ Q,
    const float* __restrict__ aux, float* __restrict__ out,
    int ldOut, int mode, const float* __restrict__ resid,
    const float* __restrict__ alphap, int aidx, double* __restrict__ stats,
    int nx) {
    __shared__ __align__(16) ushort_t As[128 * 32];
    __shared__ __align__(16) ushort_t Bs[128 * 32];
    __shared__ float cs1[4][64], cs2[4][64];
    int i0, j0;
    if (nx) {
        int blk = blockIdx.x;
        int z = blk & 7;
        int rest = blk >> 3;
        int xb = rest % nx;
        int ys = rest / nx;            // 0..15
        i0 = (z * 16 + ys) * 128;
        j0 = xb * 128;
    } else {
        i0 = blockIdx.y * 128; j0 = blockIdx.x * 128;
    }
    int tid = threadIdx.x;
    int lane = tid & 63, wave = tid >> 6;
    int wm = wave & 1, wn = wave >> 1;
    int m16 = lane & 15, kq = (lane >> 4) * 8;

    f32x4 acc[4][4];
    f32x4 zero = {0.f, 0.f, 0.f, 0.f};
#pragma unroll
    for (int i = 0; i < 4; ++i)
#pragma unroll
        for (int j = 0; j < 4; ++j) acc[i][j] = zero;

    int srow = tid >> 2;
    int skc  = (tid & 3) * 8;

    for (int k0 = 0; k0 < KP_; k0 += 32) {
        int ka = kmapA(k0), kb = kmapB(k0);
#pragma unroll
        for (int s = 0; s < 2; ++s) {
            int row = srow + s * 64;
            const ushort_t* gpA = P + (size_t)(i0 + row) * KPC_ + ka + skc;
            const ushort_t* gpB = Q + (size_t)(j0 + row) * KPC_ + kb + skc;
            __builtin_amdgcn_global_load_lds(
                (const __attribute__((address_space(1))) void*)gpA,
                (__attribute__((address_space(3))) void*)(As + (size_t)(wave * 64 + s * 256) * 8),
                16, 0, 0);
            __builtin_amdgcn_global_load_lds(
                (const __attribute__((address_space(1))) void*)gpB,
                (__attribute__((address_space(3))) void*)(Bs + (size_t)(wave * 64 + s * 256) * 8),
                16, 0, 0);
        }
        __syncthreads();
        short8 af[4], bfr[4];
#pragma unroll
        for (int fi = 0; fi < 4; ++fi)
            af[fi] = *(const short8*)(As + (wm * 64 + fi * 16 + m16) * 32 + kq);
#pragma unroll
        for (int fj = 0; fj < 4; ++fj)
            bfr[fj] = *(const short8*)(Bs + (wn * 64 + fj * 16 + m16) * 32 + kq);
#pragma unroll
        for (int fi = 0; fi < 4; ++fi)
#pragma unroll
            for (int fj = 0; fj < 4; ++fj)
                acc[fi][fj] = __builtin_amdgcn_mfma_f32_16x16x32_bf16(
                    af[fi], bfr[fj], acc[fi][fj], 0, 0, 0);
        __syncthreads();
    }
    float alpha = (mode == 2) ? alphap[aidx] : 0.f;
    int rbase = i0 + wm * 64 + (lane >> 4) * 4;
    int cbase = j0 + wn * 64 + m16;
    float s1[4] = {0.f, 0.f, 0.f, 0.f}, s2[4] = {0.f, 0.f, 0.f, 0.f};
#pragma unroll
    for (int fi = 0; fi < 4; ++fi) {
#pragma unroll
        for (int fj = 0; fj < 4; ++fj) {
            int c = cbase + fj * 16;
            float a = aux[c];
#pragma unroll
            for (int r = 0; r < 4; ++r) {
                int gr = rbase + fi * 16 + r;
                size_t oidx = (size_t)gr * ldOut + c;
                float val;
                if (mode == 2) val = resid[oidx] + alpha * (acc[fi][fj][r] + a);
                else           val = acc[fi][fj][r] + a;
                out[oidx] = val;
                s1[fj] += val; s2[fj] += val * val;
            }
        }
    }
    if (stats) {
#pragma unroll
        for (int fj = 0; fj < 4; ++fj) {
            float a1 = s1[fj], a2 = s2[fj];
            a1 += __shfl_xor(a1, 16); a1 += __shfl_xor(a1, 32);
            a2 += __shfl_xor(a2, 16); a2 += __shfl_xor(a2, 32);
            if ((lane >> 4) == 0) {
                cs1[wave][fj * 16 + m16] = a1;
                cs2[wave][fj * 16 + m16] = a2;
            }
        }
        __syncthreads();
        if (tid < 128) {
            int wnl = tid >> 6, cl = tid & 63;
            float t1 = cs1[2 * wnl][cl] + cs1[2 * wnl + 1][cl];
            float t2 = cs2[2 * wnl][cl] + cs2[2 * wnl + 1][cl];
            int c = j0 + tid;
            atomicAdd(&stats[c], (double)t1);
            atomicAdd(&stats[H_ + c], (double)t2);
        }
    }
}

// ---- gram tile body (device fn shared by gram_sym / gram_uv) ----
// D[i][j] = sq[j] - 2 <x_i, x_j>; writes both orientations when offd.
static __device__ __forceinline__ void gram_body(
    ushort_t* As, ushort_t* Bs, float* sg,
    const ushort_t* __restrict__ Pz, const float* __restrict__ sqz,
    float* __restrict__ Dz, int bi, int bj) {
    int i0 = bi * 128, j0 = bj * 128;
    int tid = threadIdx.x;
    int lane = tid & 63, wave = tid >> 6;
    int wm = wave & 1, wn = wave >> 1;
    int m16 = lane & 15, q4 = lane >> 4;
    int kq = q4 * 8;

    f32x4 acc[4][4];
    f32x4 zero = {0.f, 0.f, 0.f, 0.f};
#pragma unroll
    for (int i = 0; i < 4; ++i)
#pragma unroll
        for (int j = 0; j < 4; ++j) acc[i][j] = zero;

    int srow = tid >> 2;
    int skc  = (tid & 3) * 8;

    for (int k0 = 0; k0 < KP_; k0 += 32) {
        int ka = kmapA(k0), kb = kmapB(k0);
#pragma unroll
        for (int s = 0; s < 2; ++s) {
            int row = srow + s * 64;
            const ushort_t* gpA = Pz + (size_t)(i0 + row) * KPC_ + ka + skc;
            const ushort_t* gpB = Pz + (size_t)(j0 + row) * KPC_ + kb + skc;
            __builtin_amdgcn_global_load_lds(
                (const __attribute__((address_space(1))) void*)gpA,
                (__attribute__((address_space(3))) void*)(As + (size_t)(wave * 64 + s * 256) * 8),
                16, 0, 0);
            __builtin_amdgcn_global_load_lds(
                (const __attribute__((address_space(1))) void*)gpB,
                (__attribute__((address_space(3))) void*)(Bs + (size_t)(wave * 64 + s * 256) * 8),
                16, 0, 0);
        }
        __syncthreads();
        short8 af[4], bfr[4];
#pragma unroll
        for (int fi = 0; fi < 4; ++fi)
            af[fi] = *(const short8*)(As + (wm * 64 + fi * 16 + m16) * 32 + kq);
#pragma unroll
        for (int fj = 0; fj < 4; ++fj)
            bfr[fj] = *(const short8*)(Bs + (wn * 64 + fj * 16 + m16) * 32 + kq);
#pragma unroll
        for (int fi = 0; fi < 4; ++fi)
#pragma unroll
            for (int fj = 0; fj < 4; ++fj)
                acc[fi][fj] = __builtin_amdgcn_mfma_f32_16x16x32_bf16(
                    af[fi], bfr[fj], acc[fi][fj], 0, 0, 0);
        __syncthreads();
    }

    float scl[4];
#pragma unroll
    for (int fj = 0; fj < 4; ++fj) scl[fj] = sqz[j0 + wn * 64 + fj * 16 + m16];
    float sr[4][4];
#pragma unroll
    for (int fi = 0; fi < 4; ++fi) {
        float4 s4 = *(const float4*)(sqz + i0 + wm * 64 + fi * 16 + q4 * 4);
        sr[fi][0] = s4.x; sr[fi][1] = s4.y; sr[fi][2] = s4.z; sr[fi][3] = s4.w;
    }

    // normal orientation: per fi, wave-private [16][68] transpose -> f32x4 stores
    int rr = lane >> 2, cc = lane & 3;
#pragma unroll
    for (int fi = 0; fi < 4; ++fi) {
#pragma unroll
        for (int fj = 0; fj < 4; ++fj)
#pragma unroll
            for (int r = 0; r < 4; ++r)
                sg[(q4 * 4 + r) * 68 + fj * 16 + m16] = scl[fj] - 2.f * acc[fi][fj][r];
        float* drow = Dz + (size_t)(i0 + wm * 64 + fi * 16 + rr) * N_ + j0 + wn * 64;
#pragma unroll
        for (int t = 0; t < 4; ++t) {
            int chunk = cc + 4 * t;
            f32x4 o = *(const f32x4*)(sg + rr * 68 + chunk * 4);
            __builtin_nontemporal_store(o, (f32x4*)(drow + chunk * 4));
        }
    }

    // transposed orientation (off-diag): per fi, wave-private [64][20] -> f32x4 stores
    if (bi != bj) {
#pragma unroll
        for (int fi = 0; fi < 4; ++fi) {
#pragma unroll
            for (int fj = 0; fj < 4; ++fj)
#pragma unroll
                for (int r = 0; r < 4; ++r)
                    sg[(fj * 16 + m16) * 20 + q4 * 4 + r] =
                        sr[fi][r] - 2.f * acc[fi][fj][r];
            int chunk = lane & 3;
#pragma unroll
            for (int u = 0; u < 4; ++u) {
                int cr = (lane >> 2) + 16 * u;
                f32x4 o = *(const f32x4*)(sg + cr * 20 + chunk * 4);
                __builtin_nontemporal_store(o,
                    (f32x4*)(Dz + (size_t)(j0 + wn * 64 + cr) * N_ +
                             i0 + wm * 64 + fi * 16 + chunk * 4));
            }
        }
    }
}

// pair decode, LPT-ordered: p<120 -> off-diag pair #p (bi<bj), else diag p-120.
static __device__ __forceinline__ void pair_decode(int p, int* pbi, int* pbj) {
    if (p < 120) {
        int bi = 0, rem = p;
        while (rem >= 15 - bi) { rem -= 15 - bi; ++bi; }
        *pbi = bi; *pbj = bi + 1 + rem;
    } else {
        *pbi = *pbj = p - 120;
    }
}

// uv gemm body (mode 0, no stats, N=512, nx=4 XCD mapping), for fusion
static __device__ __forceinline__ void uvgemm_body(
    ushort_t* As, ushort_t* Bs,
    const ushort_t* __restrict__ P, const ushort_t* __restrict__ Q,
    const float* __restrict__ aux, float* __restrict__ out, int ublk) {
    int z = ublk & 7;
    int rest = ublk >> 3;
    int xb = rest & 3;
    int ys = rest >> 2;
    int i0 = (z * 16 + ys) * 128;
    int j0 = xb * 128;
    int tid = threadIdx.x;
    int lane = tid & 63, wave = tid >> 6;
    int wm = wave & 1, wn = wave >> 1;
    int m16 = lane & 15, kq = (lane >> 4) * 8;

    f32x4 acc[4][4];
    f32x4 zero = {0.f, 0.f, 0.f, 0.f};
#pragma unroll
    for (int i = 0; i < 4; ++i)
#pragma unroll
        for (int j = 0; j < 4; ++j) acc[i][j] = zero;

    int srow = tid >> 2;
    int skc  = (tid & 3) * 8;

    for (int k0 = 0; k0 < KP_; k0 += 32) {
        int ka = kmapA(k0), kb = kmapB(k0);
#pragma unroll
        for (int s = 0; s < 2; ++s) {
            int row = srow + s * 64;
            const ushort_t* gpA = P + (size_t)(i0 + row) * KPC_ + ka + skc;
            const ushort_t* gpB = Q + (size_t)(j0 + row) * KPC_ + kb + skc;
            __builtin_amdgcn_global_load_lds(
                (const __attribute__((address_space(1))) void*)gpA,
                (__attribute__((address_space(3))) void*)(As + (size_t)(wave * 64 + s * 256) * 8),
                16, 0, 0);
            __builtin_amdgcn_global_load_lds(
                (const __attribute__((address_space(1))) void*)gpB,
                (__attribute__((address_space(3))) void*)(Bs + (size_t)(wave * 64 + s * 256) * 8),
                16, 0, 0);
        }
        __syncthreads();
        short8 af[4], bfr[4];
#pragma unroll
        for (int fi = 0; fi < 4; ++fi)
            af[fi] = *(const short8*)(As + (wm * 64 + fi * 16 + m16) * 32 + kq);
#pragma unroll
        for (int fj = 0; fj < 4; ++fj)
            bfr[fj] = *(const short8*)(Bs + (wn * 64 + fj * 16 + m16) * 32 + kq);
#pragma unroll
        for (int fi = 0; fi < 4; ++fi)
#pragma unroll
            for (int fj = 0; fj < 4; ++fj)
                acc[fi][fj] = __builtin_amdgcn_mfma_f32_16x16x32_bf16(
                    af[fi], bfr[fj], acc[fi][fj], 0, 0, 0);
        __syncthreads();
    }
    int rbase = i0 + wm * 64 + (lane >> 4) * 4;
    int cbase = j0 + wn * 64 + m16;
#pragma unroll
    for (int fi = 0; fi < 4; ++fi)
#pragma unroll
        for (int fj = 0; fj < 4; ++fj) {
            int c = cbase + fj * 16;
            float a = aux[c];
#pragma unroll
            for (int r = 0; r < 4; ++r) {
                int gr = rbase + fi * 16 + r;
                out[(size_t)gr * 512 + c] = acc[fi][fj][r] + a;
            }
        }
}

// standalone symmetric gram (small path), LPT-ordered grid 1088
__global__ __launch_bounds__(256) void gram_sym(const ushort_t* __restrict__ Ap,
                                                const float* __restrict__ sqb,
                                                float* __restrict__ D) {
    __shared__ __align__(16) ushort_t As[128 * 32];
    __shared__ __align__(16) ushort_t Bs[128 * 32];
    __shared__ __align__(16) float stg[4][1280];
    int blk = blockIdx.x;
    int z = blk & 7;
    int p = (blk < 960) ? (blk >> 3) : (120 + ((blk - 960) >> 3));
    int bi, bj;
    pair_decode(p, &bi, &bj);
    gram_body(As, Bs, stg[threadIdx.x >> 6],
              Ap + (size_t)z * N_ * KPC_, sqb + (size_t)z * N_,
              D + (size_t)z * N_ * N_, bi, bj);
}

// fused gram + uv gemm (big path): blocks [0,960) off-diag gram,
// [960,1472) uv gemm (tail-filler), [1472,1600) diag gram (cheap, last).
__global__ __launch_bounds__(256) void gram_uv(const ushort_t* __restrict__ Ap,
                                               const float* __restrict__ sqb,
                                               float* __restrict__ D,
                                               const ushort_t* __restrict__ Qcat,
                                               const float* __restrict__ bcat,
                                               float* __restrict__ uv) {
    __shared__ __align__(16) ushort_t As[128 * 32];
    __shared__ __align__(16) ushort_t Bs[128 * 32];
    __shared__ __align__(16) float stg[4][1280];
    int blk = blockIdx.x;
    if (blk >= 960 && blk < 1472) {
        uvgemm_body(As, Bs, Ap, Qcat, bcat, uv, blk - 960);
        return;
    }
    int z = blk & 7;
    int p = (blk < 960) ? (blk >> 3) : (120 + ((blk - 1472) >> 3));
    int bi, bj;
    pair_decode(p, &bi, &bj);
    gram_body(As, Bs, stg[threadIdx.x >> 6],
              Ap + (size_t)z * N_ * KPC_, sqb + (size_t)z * N_,
              D + (size_t)z * N_ * N_, bi, bj);
}

// ---- threshold top-16 smallest per row (exact, lex (value,col) tie-break) ----
__global__ __launch_bounds__(256) void topk16(const float* __restrict__ D,
                                              int* __restrict__ idxb) {
    __shared__ unsigned long long cand[4][256];
    __shared__ int cnt[4];
    int w = threadIdx.x >> 6, lane = threadIdx.x & 63;
    int row = blockIdx.x * 4 + w;
    const float* dp = D + (size_t)row * N_;
    unsigned sk[32];
#pragma unroll
    for (int t = 0; t < 8; ++t) {
        f32x4 v4 = __builtin_nontemporal_load((const f32x4*)(dp + t * 256 + lane * 4));
#pragma unroll
        for (int j = 0; j < 4; ++j) {
            unsigned u = __float_as_uint(v4[j]);
            sk[t * 4 + j] = (u & 0x80000000u) ? ~u : (u | 0x80000000u);
        }
    }
    if (lane == 0) cnt[w] = 0;
    unsigned vm = sk[0];
#pragma unroll
    for (int i = 1; i < 32; ++i) vm = min(vm, sk[i]);
#pragma unroll
    for (int k = 2; k <= 64; k <<= 1) {
#pragma unroll
        for (int j = k >> 1; j > 0; j >>= 1) {
            unsigned pv = __shfl_xor(vm, j);
            bool up = ((lane & k) == 0);
            bool lower = ((lane & j) == 0);
            unsigned mn = min(vm, pv), mx = max(vm, pv);
            vm = (lower == up) ? mn : mx;
        }
    }
    unsigned T = __shfl(vm, 15);   // 16th smallest lane-min >= 16th order statistic
    __syncthreads();
#pragma unroll
    for (int i = 0; i < 32; ++i) {
        if (sk[i] <= T) {
            unsigned col = (unsigned)((i >> 2) * 256 + lane * 4 + (i & 3));
            int s = atomicAdd(&cnt[w], 1);
            if (s < 256) cand[w][s] = ((unsigned long long)sk[i] << 32) | col;
        }
    }
    __syncthreads();
    int cn = cnt[w];
    if (cn <= 64) {
        unsigned long long mykey = (lane < cn) ? cand[w][lane] : ~0ull;
        for (int it = 0; it < 16; ++it) {
            unsigned long long best = mykey;
#pragma unroll
            for (int off = 32; off; off >>= 1) {
                unsigned long long o = __shfl_xor(best, off);
                if (o < best) best = o;
            }
            if (mykey == best) mykey = ~0ull;
            if (lane == 0) idxb[row * 16 + it] = (int)(unsigned)(best & 0xffffffffu);
        }
    } else if (cn <= 256) {
        for (int it = 0; it < 16; ++it) {
            unsigned long long best = ~0ull;
            for (int i = lane; i < cn; i += 64) {
                unsigned long long c = cand[w][i];
                if (c < best) best = c;
            }
#pragma unroll
            for (int off = 32; off; off >>= 1) {
                unsigned long long o = __shfl_xor(best, off);
                if (o < best) best = o;
            }
            for (int i = lane; i < cn; i += 64)
                if (cand[w][i] == best) cand[w][i] = ~0ull;
            if (lane == 0) idxb[row * 16 + it] = (int)(unsigned)(best & 0xffffffffu);
        }
    } else {
        unsigned mask = 0;
        for (int it = 0; it < 16; ++it) {
            unsigned long long key = ~0ull;
#pragma unroll
            for (int i = 0; i < 32; ++i) {
                if (!((mask >> i) & 1u)) {
                    unsigned long long k2 = ((unsigned long long)sk[i] << 32) |
                        (unsigned)((i >> 2) * 256 + lane * 4 + (i & 3));
                    if (k2 < key) key = k2;
                }
            }
#pragma unroll
            for (int off = 32; off; off >>= 1) {
                unsigned long long o = __shfl_xor(key, off);
                if (o < key) key = o;
            }
            unsigned jc = (unsigned)(key & 0xffffffffu);
            int li = ((jc & 255) >> 2);
            int ii = ((jc >> 8) << 2) | (jc & 3);
            if (lane == li) mask |= 1u << ii;
            if (lane == 0) idxb[row * 16 + it] = (int)jc;
        }
    }
}

// t[b,i,h] = uv[row][h] + max_k uv[(b,idx_k)][256+h]; accumulates BN stats of t.
__global__ void gather_max(const float* __restrict__ uv, const int* __restrict__ idxb,
                           float* __restrict__ outp, double* __restrict__ stats) {
    int blk = blockIdx.x;
    int b = blk & 7;
    int strip = blk >> 3;               // 0..63
    int r0 = b * N_ + strip * 32;
    int f = threadIdx.x;
    float s1 = 0.f, s2 = 0.f;
    for (int rr = 0; rr < 32; ++rr) {
        int row = r0 + rr;
        const int* ip = idxb + row * 16;
        float m = -FLT_MAX;
#pragma unroll
        for (int k = 0; k < 16; ++k) {
            int j = ip[k];
            m = fmaxf(m, uv[((size_t)((b << 11) + j)) * 512 + 256 + f]);
        }
        float v = uv[(size_t)row * 512 + f] + m;
        outp[(size_t)row * H_ + f] = v;
        s1 += v; s2 += v * v;
    }
    atomicAdd(&stats[f], (double)s1);
    atomicAdd(&stats[H_ + f], (double)s2);
}

// BN+ReLU fused with compact split-bf16 packing and optional row sqnorm reduce.
// scale/shift computed in-block from the stats slot (bitwise-identical).
__global__ void bn_apply_pack(const float* __restrict__ X, const double* __restrict__ sums,
                              const float* __restrict__ g, const float* __restrict__ b,
                              ushort_t* __restrict__ Ap, float* __restrict__ sq) {
    __shared__ float scsh[512];
    int tid = threadIdx.x;
    {
        double m  = sums[tid] / (double)BN_;
        double var = sums[H_ + tid] / (double)BN_ - m * m;
        double inv = 1.0 / sqrt(var + 1e-5);
        float sc = g[tid] * (float)inv;
        scsh[tid] = sc;
        scsh[H_ + tid] = b[tid] - (float)m * sc;
    }
    __syncthreads();
    int row = blockIdx.x * 8 + (tid >> 5);
    int f0  = (tid & 31) * 8;
    const float* xp = X + (size_t)row * H_ + f0;
    f32x4 x0 = *(const f32x4*)(xp);
    f32x4 x1 = *(const f32x4*)(xp + 4);
    f32x4 sc0 = *(const f32x4*)(scsh + f0);
    f32x4 sc1 = *(const f32x4*)(scsh + f0 + 4);
    f32x4 sh0 = *(const f32x4*)(scsh + H_ + f0);
    f32x4 sh1 = *(const f32x4*)(scsh + H_ + f0 + 4);
    float v[8];
#pragma unroll
    for (int i = 0; i < 4; ++i) {
        v[i]     = fmaxf(x0[i] * sc0[i] + sh0[i], 0.f);
        v[i + 4] = fmaxf(x1[i] * sc1[i] + sh1[i], 0.f);
    }
    short8 hi8, lo8;
#pragma unroll
    for (int i = 0; i < 8; ++i) {
        ushort_t hi = f2bf(v[i]);
        ushort_t lo = f2bf(v[i] - bf2f(hi));
        hi8[i] = (short)hi; lo8[i] = (short)lo;
    }
    ushort_t* ap = Ap + (size_t)row * KPC_ + f0;
    *(short8*)(ap)      = hi8;
    *(short8*)(ap + H_) = lo8;
    if (sq) {
        float s = 0.f;
#pragma unroll
        for (int i = 0; i < 8; ++i) s += v[i] * v[i];
#pragma unroll
        for (int off = 16; off; off >>= 1) s += __shfl_down(s, off, 32);
        if ((tid & 31) == 0) sq[row] = s;
    }
}

// head gemm (N=512) with fused n-chunk maxpool: never materializes y.
// Block (z, ys, xb) covers batch z, rows [ys*128,(ys+1)*128), cols [xb*128,+128);
// in-block fmax over the 128 rows -> pmax[(z*16+ys)*512 + col]. Exact (max assoc.).
__global__ __launch_bounds__(256) void head_gemm_pool(
    const ushort_t* __restrict__ P, const ushort_t* __restrict__ Q,
    const float* __restrict__ aux, float* __restrict__ pmax) {
    __shared__ __align__(16) ushort_t As[128 * 32];
    __shared__ __align__(16) ushort_t Bs[128 * 32];
    __shared__ float smax[2][2][64];
    int blk = blockIdx.x;
    int z = blk & 7;
    int rest = blk >> 3;
    int xb = rest & 3;
    int ys = rest >> 2;
    int i0 = (z * 16 + ys) * 128;
    int j0 = xb * 128;
    int tid = threadIdx.x;
    int lane = tid & 63, wave = tid >> 6;
    int wm = wave & 1, wn = wave >> 1;
    int m16 = lane & 15, kq = (lane >> 4) * 8;

    f32x4 acc[4][4];
    f32x4 zero = {0.f, 0.f, 0.f, 0.f};
#pragma unroll
    for (int i = 0; i < 4; ++i)
#pragma unroll
        for (int j = 0; j < 4; ++j) acc[i][j] = zero;

    int srow = tid >> 2;
    int skc  = (tid & 3) * 8;

    for (int k0 = 0; k0 < KP_; k0 += 32) {
        int ka = kmapA(k0), kb = kmapB(k0);
#pragma unroll
        for (int s = 0; s < 2; ++s) {
            int row = srow + s * 64;
            const ushort_t* gpA = P + (size_t)(i0 + row) * KPC_ + ka + skc;
            const ushort_t* gpB = Q + (size_t)(j0 + row) * KPC_ + kb + skc;
            __builtin_amdgcn_global_load_lds(
                (const __attribute__((address_space(1))) void*)gpA,
                (__attribute__((address_space(3))) void*)(As + (size_t)(wave * 64 + s * 256) * 8),
                16, 0, 0);
            __builtin_amdgcn_global_load_lds(
                (const __attribute__((address_space(1))) void*)gpB,
                (__attribute__((address_space(3))) void*)(Bs + (size_t)(wave * 64 + s * 256) * 8),
                16, 0, 0);
        }
        __syncthreads();
        short8 af[4], bfr[4];
#pragma unroll
        for (int fi = 0; fi < 4; ++fi)
            af[fi] = *(const short8*)(As + (wm * 64 + fi * 16 + m16) * 32 + kq);
#pragma unroll
        for (int fj = 0; fj < 4; ++fj)
            bfr[fj] = *(const short8*)(Bs + (wn * 64 + fj * 16 + m16) * 32 + kq);
#pragma unroll
        for (int fi = 0; fi < 4; ++fi)
#pragma unroll
            for (int fj = 0; fj < 4; ++fj)
                acc[fi][fj] = __builtin_amdgcn_mfma_f32_16x16x32_bf16(
                    af[fi], bfr[fj], acc[fi][fj], 0, 0, 0);
        __syncthreads();
    }
    float vmax[4];
#pragma unroll
    for (int fj = 0; fj < 4; ++fj) {
        int c = j0 + wn * 64 + m16 + fj * 16;
        float a = aux[c];
        float m = -FLT_MAX;
#pragma unroll
        for (int fi = 0; fi < 4; ++fi)
#pragma unroll
            for (int r = 0; r < 4; ++r)
                m = fmaxf(m, acc[fi][fj][r] + a);
        m = fmaxf(m, __shfl_xor(m, 16));
        m = fmaxf(m, __shfl_xor(m, 32));
        vmax[fj] = m;
    }
    if (lane < 16) {
#pragma unroll
        for (int fj = 0; fj < 4; ++fj)
            smax[wm][wn][fj * 16 + m16] = vmax[fj];
    }
    __syncthreads();
    if (tid < 128) {
        int wn2 = tid >> 6, off = tid & 63;
        float m = fmaxf(smax[0][wn2][off], smax[1][wn2][off]);
        pmax[((size_t)(z * 16 + ys)) * G_ + j0 + wn2 * 64 + off] = m;
    }
}

// fused head: 16-chunk maxpool + 3-layer MLP (replicates the proven 4-way
// K-split and red[0..3]+bias summation order -> bitwise-identical).
__global__ __launch_bounds__(256) void head3(const float* __restrict__ pmax,
    const float* __restrict__ Wm1, const float* __restrict__ bm1,
    const float* __restrict__ Wm2, const float* __restrict__ bm2,
    const float* __restrict__ Wm3, const float* __restrict__ bm3,
    float* __restrict__ out) {
    __shared__ float s0[512];
    __shared__ float s1[256];
    __shared__ float red[4][64];
    int b = blockIdx.x, tid = threadIdx.x;
    {
        float m0 = -FLT_MAX, m1 = -FLT_MAX;
        for (int c2 = 0; c2 < 16; ++c2) {
            m0 = fmaxf(m0, pmax[((size_t)(b * 16 + c2)) * G_ + tid]);
            m1 = fmaxf(m1, pmax[((size_t)(b * 16 + c2)) * G_ + 256 + tid]);
        }
        s0[tid] = m0; s0[256 + tid] = m1;
    }
    int cl = tid & 63, ks = tid >> 6;
    __syncthreads();
    // stage 1: 256 outs, K=512 (kper=128)
    for (int cg = 0; cg < 4; ++cg) {
        int c = cg * 64 + cl;
        const float* Apt = s0 + ks * 128;
        const float* Wp  = Wm1 + (size_t)(ks * 128) * M0_ + c;
        float acc = 0.f;
        for (int k = 0; k < 128; k += 8)
#pragma unroll
            for (int u2 = 0; u2 < 8; ++u2)
                acc += Apt[k + u2] * Wp[(size_t)(k + u2) * M0_];
        red[ks][cl] = acc;
        __syncthreads();
        if (ks == 0) {
            float s = red[0][cl] + red[1][cl] + red[2][cl] + red[3][cl] + bm1[c];
            s1[c] = fmaxf(s, 0.f);
        }
        __syncthreads();
    }
    // stage 2: 128 outs, K=256 (kper=64)
    float s2v[2];
    for (int cg = 0; cg < 2; ++cg) {
        int c = cg * 64 + cl;
        const float* Apt = s1 + ks * 64;
        const float* Wp  = Wm2 + (size_t)(ks * 64) * M1_ + c;
        float acc = 0.f;
        for (int k = 0; k < 64; k += 8)
#pragma unroll
            for (int u2 = 0; u2 < 8; ++u2)
                acc += Apt[k + u2] * Wp[(size_t)(k + u2) * M1_];
        red[ks][cl] = acc;
        __syncthreads();
        s2v[cg] = 0.f;
        if (ks == 0) {
            float s = red[0][cl] + red[1][cl] + red[2][cl] + red[3][cl] + bm2[c];
            s2v[cg] = fmaxf(s, 0.f);
        }
        __syncthreads();
    }
    if (ks == 0) { s0[cl] = s2v[0]; s0[64 + cl] = s2v[1]; }
    __syncthreads();
    // stage 3: 128 outs, K=128 (kper=32)
    for (int cg = 0; cg < 2; ++cg) {
        int c = cg * 64 + cl;
        const float* Apt = s0 + ks * 32;
        const float* Wp  = Wm3 + (size_t)(ks * 32) * C_ + c;
        float acc = 0.f;
        for (int k = 0; k < 32; k += 8)
#pragma unroll
            for (int u2 = 0; u2 < 8; ++u2)
                acc += Apt[k + u2] * Wp[(size_t)(k + u2) * C_];
        red[ks][cl] = acc;
        __syncthreads();
        if (ks == 0)
            out[(size_t)b * C_ + c] =
                red[0][cl] + red[1][cl] + red[2][cl] + red[3][cl] + bm3[c];
        __syncthreads();
    }
}

// ---------------- launch ----------------
extern "C" void kernel_launch(void* const* d_in, const int* in_sizes, int n_in,
                              void* d_out, int out_size, void* d_ws, size_t ws_size,
                              hipStream_t stream) {
    (void)in_sizes; (void)n_in; (void)out_size;
    if (ws_size < WS_SMALL) return;
    const bool big = (ws_size >= WS_BIG);

    const float* x    = (const float*)d_in[0];
    const float* Wf   = (const float*)d_in[2];
    const float* bfv  = (const float*)d_in[3];
    const float* Wnn  = (const float*)d_in[4];
    const float* bnn  = (const float*)d_in[5];
    const float* g1   = (const float*)d_in[6];
    const float* b1   = (const float*)d_in[7];
    const float* We   = (const float*)d_in[8];
    const float* be   = (const float*)d_in[9];
    const float* g2   = (const float*)d_in[10];
    const float* b2   = (const float*)d_in[11];
    const float* Wl   = (const float*)d_in[12];
    const float* bl   = (const float*)d_in[13];
    const float* alpha= (const float*)d_in[14];
    const float* gg   = (const float*)d_in[15];
    const float* bgb  = (const float*)d_in[16];
    const float* Wg   = (const float*)d_in[17];
    const float* bg2  = (const float*)d_in[18];
    const float* Wm1  = (const float*)d_in[19];
    const float* bm1  = (const float*)d_in[20];
    const float* Wm2  = (const float*)d_in[21];
    const float* bm2  = (const float*)d_in[22];
    const float* Wm3  = (const float*)d_in[23];
    const float* bm3  = (const float*)d_in[24];
    float* outp = (float*)d_out;

    char* ws = (char*)d_ws;
    float*    h    = (float*)(ws + OFF_H);
    ushort_t* Ap   = (ushort_t*)(ws + OFF_APACK);
    ushort_t* Qpk  = (ushort_t*)(ws + OFF_WPK);
    float*    bcatA= (float*)(ws + OFF_BCA);
    double*   sta  = (double*)(ws + OFF_STA);
    float*    sqb  = (float*)(ws + OFF_SQ);
    int*      idxb = (int*)  (ws + OFF_IDX);

    size_t offD = big ? OFF_DBIG : OFF_DSML;
    float*    dmat = (float*)(ws + offD);
    float*    t    = (float*)(ws + offD);                      // overlays D (dead)
    float*    uv   = big ? (float*)(ws + OFF_UVBIG)
                         : (float*)(ws + offD + (size_t)50331648);
    float*    pmax = (float*)(ws + offD + (size_t)84672512);   // overlays D (dead)

    ushort_t* Qwnn = Qpk + (size_t)WPK_WNN * KPC_;
    ushort_t* Qwg  = Qpk + (size_t)WPK_WG  * KPC_;

    // fused prep: feat+pack | weight packs | stats zero
    hipLaunchKernelGGL(prep, dim3(BN_ + 3840 + 9), dim3(256), 0, stream,
                       x, Wf, bfv, h, Ap, Wnn, Wl, Wg, We, be, Qpk, bcatA, sta);

    // t = h@Wnn+bnn via MFMA (t-stats -> slot 0), XCD-pinned
    hipLaunchKernelGGL(mfma_gemm, dim3(256), dim3(256), 0, stream,
                       Ap, Qwnn, bnn, t, H_, 0,
                       (const float*)nullptr, (const float*)nullptr, 0, sta, 2);

    for (int l = 0; l < L_; ++l) {
        const float* src1 = (l == 0) ? t : h;
        hipLaunchKernelGGL(bn_apply_pack, dim3(BN_ / 8), dim3(256), 0, stream,
                           src1, sta + (size_t)(2 * l) * 512,
                           g1 + l * H_, b1 + l * H_, Ap, sqb);
        if (big) {
            // fused: gram (off-diag first, diag last) + uv gemm tail-filler
            hipLaunchKernelGGL(gram_uv, dim3(1600), dim3(256), 0, stream,
                               Ap, sqb, dmat,
                               Qpk + (size_t)(WPK_QCAT + l * 512) * KPC_,
                               bcatA + (size_t)l * 512, uv);
            hipLaunchKernelGGL(topk16, dim3(BN_ / 4), dim3(256), 0, stream, dmat, idxb);
        } else {
            hipLaunchKernelGGL(gram_sym, dim3(1088), dim3(256), 0, stream,
                               Ap, sqb, dmat);
            hipLaunchKernelGGL(topk16, dim3(BN_ / 4), dim3(256), 0, stream, dmat, idxb);
            hipLaunchKernelGGL(mfma_gemm, dim3(512), dim3(256), 0, stream,
                               Ap, Qpk + (size_t)(WPK_QCAT + l * 512) * KPC_,
                               bcatA + (size_t)l * 512, uv, 512, 0,
                               (const float*)nullptr, (const float*)nullptr, 0,
                               (double*)nullptr, 4);
        }
        hipLaunchKernelGGL(gather_max, dim3(512), dim3(256), 0, stream,
                           uv, idxb, t, sta + (size_t)(2 * l + 1) * 512);
        hipLaunchKernelGGL(bn_apply_pack, dim3(BN_ / 8), dim3(256), 0, stream,
                           t, sta + (size_t)(2 * l + 1) * 512,
                           g2 + l * H_, b2 + l * H_, Ap, (float*)nullptr);
        hipLaunchKernelGGL(mfma_gemm, dim3(256), dim3(256), 0, stream,
                           Ap, Qpk + (size_t)(WPK_WL + l * 256) * KPC_,
                           bl + (size_t)l * H_, h, H_, 2,
                           h, alpha, l, sta + (size_t)(2 * l + 2) * 512, 2);
    }

    // head: BN from slot 8, pack, fused Wg-gemm+pool, fused pool2+MLP
    hipLaunchKernelGGL(bn_apply_pack, dim3(BN_ / 8), dim3(256), 0, stream,
                       h, sta + (size_t)8 * 512, gg, bgb, Ap, (float*)nullptr);
    hipLaunchKernelGGL(head_gemm_pool, dim3(512), dim3(256), 0, stream,
                       Ap, Qwg, bg2, pmax);
    hipLaunchKernelGGL(head3, dim3(8), dim3(256), 0, stream,
                       pmax, Wm1, bm1, Wm2, bm2, Wm3, bm3, outp);
}

// Round 5
// 1007.924 us; speedup vs baseline: 1.3796x; 1.0397x over previous
//
#include <hip/hip_runtime.h>
#include <cfloat>

#define B_  8
#define N_  2048
#define H_  256
#define L_  4
#define K_  16
#define G_  512
#define M0_ 256
#define M1_ 128
#define C_  128
#define BN_ 16384   // B_*N_
#define KP_ 768     // effective split-bf16 K (3*H_)
#define KPC_ 512    // compact pack row stride [hi(0:256) | lo(256:512)]

typedef unsigned short ushort_t;
typedef __attribute__((ext_vector_type(8))) short short8;
typedef __attribute__((ext_vector_type(4))) float f32x4;

// ---------------- workspace layout (bytes) ----------------
// shared fixed region
#define OFF_H     ((size_t)0)            // 16 MB   h (fp32, persistent)
#define OFF_APACK ((size_t)16777216)     // 16.8 MB compact P-pack [hi|lo]
#define OFF_WPK   ((size_t)33554432)     // 3.93 MB all weight packs (3840 x 512 bf16)
#define OFF_BCA   ((size_t)37486592)     // 8 KB    bcat arena
#define OFF_STA   ((size_t)37494784)     // 36 KB   stats arena (9 x 512 doubles)
#define OFF_SQ    ((size_t)37531648)     // 64 KB
#define OFF_IDX   ((size_t)37597184)     // 1 MB -> ends 38,645,760
// big path: uv gets its own home (so it can be written concurrently with D)
#define OFF_UVBIG ((size_t)38645760)     // 33.5 MB -> ends 72,200,192
#define OFF_DSML  ((size_t)69206016)     // small path D (uv/t/pmax overlay inside)
#define OFF_DBIG  ((size_t)72200192)     // big path D
#define WS_SMALL  ((size_t)203423744)    // OFF_DSML + 134,217,728
#define WS_BIG    ((size_t)206417920)    // OFF_DBIG + 134,217,728

// weight-pack arena row offsets
#define WPK_WNN   0
#define WPK_WL    256      // + l*256
#define WPK_WG    1280
#define WPK_QCAT  1792     // + l*512

// ---------------- helpers ----------------
static __device__ __forceinline__ ushort_t f2bf(float f) {
    unsigned u = __float_as_uint(f);
    unsigned r = (u + 0x7fffu + ((u >> 16) & 1u)) >> 16;   // RNE
    return (ushort_t)r;
}
static __device__ __forceinline__ float bf2f(ushort_t h) {
    return __uint_as_float(((unsigned)h) << 16);
}
// segment remaps on the compact [hi|lo] pack.
// A-side effective order [hi,lo,hi]; B-side effective order [hi,hi,lo].
static __device__ __forceinline__ int kmapA(int k0) { return (k0 < KPC_) ? k0 : k0 - KPC_; }
static __device__ __forceinline__ int kmapB(int k0) { return (k0 < 256)  ? k0 : k0 - 256; }

// ---------------- fused prep: feat_pack + pack_all + stats zero ----------------
__global__ void prep(const float* __restrict__ x, const float* __restrict__ Wf,
                     const float* __restrict__ bfv, float* __restrict__ h,
                     ushort_t* __restrict__ Ap,
                     const float* __restrict__ Wnn, const float* __restrict__ Wl,
                     const float* __restrict__ Wg, const float* __restrict__ We,
                     const float* __restrict__ be, ushort_t* __restrict__ Qp,
                     float* __restrict__ bcat, double* __restrict__ sta) {
    int blk = blockIdx.x;
    int tid = threadIdx.x;
    if (blk < BN_) {
        int pt = blk, f = tid;
        float x0 = x[pt * 3 + 0], x1 = x[pt * 3 + 1], x2 = x[pt * 3 + 2];
        float v = x0 * Wf[f] + x1 * Wf[H_ + f] + x2 * Wf[2 * H_ + f] + bfv[f];
        h[(size_t)pt * H_ + f] = v;
        ushort_t hi = f2bf(v), lo = f2bf(v - bf2f(hi));
        size_t base = (size_t)pt * KPC_;
        Ap[base + f] = hi; Ap[base + H_ + f] = lo;
    } else if (blk < BN_ + 3840) {
        int row = blk - BN_, k = tid;
        float w;
        if (row < 1792) {
            const float* W; int Nd, n;
            if (row < 256)        { W = Wnn; Nd = 256; n = row; }
            else if (row < 1280)  { int l = (row - 256) >> 8;
                                    W = Wl + (size_t)l * (H_ * H_); Nd = 256; n = (row - 256) & 255; }
            else                  { W = Wg; Nd = 512; n = row - 1280; }
            w = W[(size_t)k * Nd + n];
        } else {
            int rr = row - 1792; int l = rr >> 9; int n = rr & 511;
            const float* We_l = We + (size_t)l * 2 * H_ * H_;
            if (n < H_) w = We_l[(size_t)k * H_ + n] - We_l[(size_t)H_ * H_ + (size_t)k * H_ + n];
            else        w = We_l[(size_t)H_ * H_ + (size_t)k * H_ + (n - H_)];
            if (k == 0) bcat[l * 512 + n] = (n < H_) ? be[l * H_ + n] : 0.f;
        }
        ushort_t hi = f2bf(w), lo = f2bf(w - bf2f(hi));
        size_t base = (size_t)row * KPC_;
        Qp[base + k] = hi; Qp[base + H_ + k] = lo;
    } else {
        int slot = blk - (BN_ + 3840);
        sta[(size_t)slot * 512 + tid] = 0.0;
        sta[(size_t)slot * 512 + 256 + tid] = 0.0;
    }
}

// ---- split-bf16 MFMA GEMM core (compact packs, K=768 via remaps) ----
// mode 0: out[r][c] = acc + aux[c]
// mode 2: out[r][c] = resid[r][c] + alphap[aidx]*(acc+aux[c])
// stats != nullptr: accumulate per-column sum/sumsq of written values
// nx != 0: 1-D grid of nx*128 blocks, XCD-pinned: z=blk&7 owns batch z's rows.
__global__ __launch_bounds__(256) void mfma_gemm(
    const ushort_t* __restrict__ P, const ushort_t* __restrict__ Q,
    const float* __restrict__ aux, float* __restrict__ out,
    int ldOut, int mode, const float* __restrict__ resid,
    const float* __restrict__ alphap, int aidx, double* __restrict__ stats,
    int nx) {
    __shared__ __align__(16) ushort_t As[128 * 32];
    __shared__ __align__(16) ushort_t Bs[128 * 32];
    __shared__ float cs1[4][64], cs2[4][64];
    int i0, j0;
    if (nx) {
        int blk = blockIdx.x;
        int z = blk & 7;
        int rest = blk >> 3;
        int xb = rest % nx;
        int ys = rest / nx;            // 0..15
        i0 = (z * 16 + ys) * 128;
        j0 = xb * 128;
    } else {
        i0 = blockIdx.y * 128; j0 = blockIdx.x * 128;
    }
    int tid = threadIdx.x;
    int lane = tid & 63, wave = tid >> 6;
    int wm = wave & 1, wn = wave >> 1;
    int m16 = lane & 15, kq = (lane >> 4) * 8;

    f32x4 acc[4][4];
    f32x4 zero = {0.f, 0.f, 0.f, 0.f};
#pragma unroll
    for (int i = 0; i < 4; ++i)
#pragma unroll
        for (int j = 0; j < 4; ++j) acc[i][j] = zero;

    int srow = tid >> 2;
    int skc  = (tid & 3) * 8;

    for (int k0 = 0; k0 < KP_; k0 += 32) {
        int ka = kmapA(k0), kb = kmapB(k0);
#pragma unroll
        for (int s = 0; s < 2; ++s) {
            int row = srow + s * 64;
            const ushort_t* gpA = P + (size_t)(i0 + row) * KPC_ + ka + skc;
            const ushort_t* gpB = Q + (size_t)(j0 + row) * KPC_ + kb + skc;
            __builtin_amdgcn_global_load_lds(
                (const __attribute__((address_space(1))) void*)gpA,
                (__attribute__((address_space(3))) void*)(As + (size_t)(wave * 64 + s * 256) * 8),
                16, 0, 0);
            __builtin_amdgcn_global_load_lds(
                (const __attribute__((address_space(1))) void*)gpB,
                (__attribute__((address_space(3))) void*)(Bs + (size_t)(wave * 64 + s * 256) * 8),
                16, 0, 0);
        }
        __syncthreads();
        short8 af[4], bfr[4];
#pragma unroll
        for (int fi = 0; fi < 4; ++fi)
            af[fi] = *(const short8*)(As + (wm * 64 + fi * 16 + m16) * 32 + kq);
#pragma unroll
        for (int fj = 0; fj < 4; ++fj)
            bfr[fj] = *(const short8*)(Bs + (wn * 64 + fj * 16 + m16) * 32 + kq);
#pragma unroll
        for (int fi = 0; fi < 4; ++fi)
#pragma unroll
            for (int fj = 0; fj < 4; ++fj)
                acc[fi][fj] = __builtin_amdgcn_mfma_f32_16x16x32_bf16(
                    af[fi], bfr[fj], acc[fi][fj], 0, 0, 0);
        __syncthreads();
    }
    float alpha = (mode == 2) ? alphap[aidx] : 0.f;
    int rbase = i0 + wm * 64 + (lane >> 4) * 4;
    int cbase = j0 + wn * 64 + m16;
    float s1[4] = {0.f, 0.f, 0.f, 0.f}, s2[4] = {0.f, 0.f, 0.f, 0.f};
#pragma unroll
    for (int fi = 0; fi < 4; ++fi) {
#pragma unroll
        for (int fj = 0; fj < 4; ++fj) {
            int c = cbase + fj * 16;
            float a = aux[c];
#pragma unroll
            for (int r = 0; r < 4; ++r) {
                int gr = rbase + fi * 16 + r;
                size_t oidx = (size_t)gr * ldOut + c;
                float val;
                if (mode == 2) val = resid[oidx] + alpha * (acc[fi][fj][r] + a);
                else           val = acc[fi][fj][r] + a;
                out[oidx] = val;
                s1[fj] += val; s2[fj] += val * val;
            }
        }
    }
    if (stats) {
#pragma unroll
        for (int fj = 0; fj < 4; ++fj) {
            float a1 = s1[fj], a2 = s2[fj];
            a1 += __shfl_xor(a1, 16); a1 += __shfl_xor(a1, 32);
            a2 += __shfl_xor(a2, 16); a2 += __shfl_xor(a2, 32);
            if ((lane >> 4) == 0) {
                cs1[wave][fj * 16 + m16] = a1;
                cs2[wave][fj * 16 + m16] = a2;
            }
        }
        __syncthreads();
        if (tid < 128) {
            int wnl = tid >> 6, cl = tid & 63;
            float t1 = cs1[2 * wnl][cl] + cs1[2 * wnl + 1][cl];
            float t2 = cs2[2 * wnl][cl] + cs2[2 * wnl + 1][cl];
            int c = j0 + tid;
            atomicAdd(&stats[c], (double)t1);
            atomicAdd(&stats[H_ + c], (double)t2);
        }
    }
}

// ---- gram tile body (device fn shared by gram_sym / gram_uv) ----
// D[i][j] = sq[j] - 2 <x_i, x_j>; writes both orientations when offd.
// D stores are CACHEABLE (not NT): D (134 MB) + Ap + uv fit the 256 MB LLC,
// so topk16's full re-read one kernel later hits LLC instead of HBM.
static __device__ __forceinline__ void gram_body(
    ushort_t* As, ushort_t* Bs, float* sg,
    const ushort_t* __restrict__ Pz, const float* __restrict__ sqz,
    float* __restrict__ Dz, int bi, int bj) {
    int i0 = bi * 128, j0 = bj * 128;
    int tid = threadIdx.x;
    int lane = tid & 63, wave = tid >> 6;
    int wm = wave & 1, wn = wave >> 1;
    int m16 = lane & 15, q4 = lane >> 4;
    int kq = q4 * 8;

    f32x4 acc[4][4];
    f32x4 zero = {0.f, 0.f, 0.f, 0.f};
#pragma unroll
    for (int i = 0; i < 4; ++i)
#pragma unroll
        for (int j = 0; j < 4; ++j) acc[i][j] = zero;

    int srow = tid >> 2;
    int skc  = (tid & 3) * 8;

    for (int k0 = 0; k0 < KP_; k0 += 32) {
        int ka = kmapA(k0), kb = kmapB(k0);
#pragma unroll
        for (int s = 0; s < 2; ++s) {
            int row = srow + s * 64;
            const ushort_t* gpA = Pz + (size_t)(i0 + row) * KPC_ + ka + skc;
            const ushort_t* gpB = Pz + (size_t)(j0 + row) * KPC_ + kb + skc;
            __builtin_amdgcn_global_load_lds(
                (const __attribute__((address_space(1))) void*)gpA,
                (__attribute__((address_space(3))) void*)(As + (size_t)(wave * 64 + s * 256) * 8),
                16, 0, 0);
            __builtin_amdgcn_global_load_lds(
                (const __attribute__((address_space(1))) void*)gpB,
                (__attribute__((address_space(3))) void*)(Bs + (size_t)(wave * 64 + s * 256) * 8),
                16, 0, 0);
        }
        __syncthreads();
        short8 af[4], bfr[4];
#pragma unroll
        for (int fi = 0; fi < 4; ++fi)
            af[fi] = *(const short8*)(As + (wm * 64 + fi * 16 + m16) * 32 + kq);
#pragma unroll
        for (int fj = 0; fj < 4; ++fj)
            bfr[fj] = *(const short8*)(Bs + (wn * 64 + fj * 16 + m16) * 32 + kq);
#pragma unroll
        for (int fi = 0; fi < 4; ++fi)
#pragma unroll
            for (int fj = 0; fj < 4; ++fj)
                acc[fi][fj] = __builtin_amdgcn_mfma_f32_16x16x32_bf16(
                    af[fi], bfr[fj], acc[fi][fj], 0, 0, 0);
        __syncthreads();
    }

    float scl[4];
#pragma unroll
    for (int fj = 0; fj < 4; ++fj) scl[fj] = sqz[j0 + wn * 64 + fj * 16 + m16];
    float sr[4][4];
#pragma unroll
    for (int fi = 0; fi < 4; ++fi) {
        float4 s4 = *(const float4*)(sqz + i0 + wm * 64 + fi * 16 + q4 * 4);
        sr[fi][0] = s4.x; sr[fi][1] = s4.y; sr[fi][2] = s4.z; sr[fi][3] = s4.w;
    }

    // normal orientation: per fi, wave-private [16][68] transpose -> f32x4 stores
    int rr = lane >> 2, cc = lane & 3;
#pragma unroll
    for (int fi = 0; fi < 4; ++fi) {
#pragma unroll
        for (int fj = 0; fj < 4; ++fj)
#pragma unroll
            for (int r = 0; r < 4; ++r)
                sg[(q4 * 4 + r) * 68 + fj * 16 + m16] = scl[fj] - 2.f * acc[fi][fj][r];
        float* drow = Dz + (size_t)(i0 + wm * 64 + fi * 16 + rr) * N_ + j0 + wn * 64;
#pragma unroll
        for (int t = 0; t < 4; ++t) {
            int chunk = cc + 4 * t;
            f32x4 o = *(const f32x4*)(sg + rr * 68 + chunk * 4);
            *(f32x4*)(drow + chunk * 4) = o;
        }
    }

    // transposed orientation (off-diag): per fi, wave-private [64][20] -> f32x4 stores
    if (bi != bj) {
#pragma unroll
        for (int fi = 0; fi < 4; ++fi) {
#pragma unroll
            for (int fj = 0; fj < 4; ++fj)
#pragma unroll
                for (int r = 0; r < 4; ++r)
                    sg[(fj * 16 + m16) * 20 + q4 * 4 + r] =
                        sr[fi][r] - 2.f * acc[fi][fj][r];
            int chunk = lane & 3;
#pragma unroll
            for (int u = 0; u < 4; ++u) {
                int cr = (lane >> 2) + 16 * u;
                f32x4 o = *(const f32x4*)(sg + cr * 20 + chunk * 4);
                *(f32x4*)(Dz + (size_t)(j0 + wn * 64 + cr) * N_ +
                          i0 + wm * 64 + fi * 16 + chunk * 4) = o;
            }
        }
    }
}

// pair decode, LPT-ordered: p<120 -> off-diag pair #p (bi<bj), else diag p-120.
static __device__ __forceinline__ void pair_decode(int p, int* pbi, int* pbj) {
    if (p < 120) {
        int bi = 0, rem = p;
        while (rem >= 15 - bi) { rem -= 15 - bi; ++bi; }
        *pbi = bi; *pbj = bi + 1 + rem;
    } else {
        *pbi = *pbj = p - 120;
    }
}

// uv gemm body (mode 0, no stats, N=512, nx=4 XCD mapping), for fusion
static __device__ __forceinline__ void uvgemm_body(
    ushort_t* As, ushort_t* Bs,
    const ushort_t* __restrict__ P, const ushort_t* __restrict__ Q,
    const float* __restrict__ aux, float* __restrict__ out, int ublk) {
    int z = ublk & 7;
    int rest = ublk >> 3;
    int xb = rest & 3;
    int ys = rest >> 2;
    int i0 = (z * 16 + ys) * 128;
    int j0 = xb * 128;
    int tid = threadIdx.x;
    int lane = tid & 63, wave = tid >> 6;
    int wm = wave & 1, wn = wave >> 1;
    int m16 = lane & 15, kq = (lane >> 4) * 8;

    f32x4 acc[4][4];
    f32x4 zero = {0.f, 0.f, 0.f, 0.f};
#pragma unroll
    for (int i = 0; i < 4; ++i)
#pragma unroll
        for (int j = 0; j < 4; ++j) acc[i][j] = zero;

    int srow = tid >> 2;
    int skc  = (tid & 3) * 8;

    for (int k0 = 0; k0 < KP_; k0 += 32) {
        int ka = kmapA(k0), kb = kmapB(k0);
#pragma unroll
        for (int s = 0; s < 2; ++s) {
            int row = srow + s * 64;
            const ushort_t* gpA = P + (size_t)(i0 + row) * KPC_ + ka + skc;
            const ushort_t* gpB = Q + (size_t)(j0 + row) * KPC_ + kb + skc;
            __builtin_amdgcn_global_load_lds(
                (const __attribute__((address_space(1))) void*)gpA,
                (__attribute__((address_space(3))) void*)(As + (size_t)(wave * 64 + s * 256) * 8),
                16, 0, 0);
            __builtin_amdgcn_global_load_lds(
                (const __attribute__((address_space(1))) void*)gpB,
                (__attribute__((address_space(3))) void*)(Bs + (size_t)(wave * 64 + s * 256) * 8),
                16, 0, 0);
        }
        __syncthreads();
        short8 af[4], bfr[4];
#pragma unroll
        for (int fi = 0; fi < 4; ++fi)
            af[fi] = *(const short8*)(As + (wm * 64 + fi * 16 + m16) * 32 + kq);
#pragma unroll
        for (int fj = 0; fj < 4; ++fj)
            bfr[fj] = *(const short8*)(Bs + (wn * 64 + fj * 16 + m16) * 32 + kq);
#pragma unroll
        for (int fi = 0; fi < 4; ++fi)
#pragma unroll
            for (int fj = 0; fj < 4; ++fj)
                acc[fi][fj] = __builtin_amdgcn_mfma_f32_16x16x32_bf16(
                    af[fi], bfr[fj], acc[fi][fj], 0, 0, 0);
        __syncthreads();
    }
    int rbase = i0 + wm * 64 + (lane >> 4) * 4;
    int cbase = j0 + wn * 64 + m16;
#pragma unroll
    for (int fi = 0; fi < 4; ++fi)
#pragma unroll
        for (int fj = 0; fj < 4; ++fj) {
            int c = cbase + fj * 16;
            float a = aux[c];
#pragma unroll
            for (int r = 0; r < 4; ++r) {
                int gr = rbase + fi * 16 + r;
                out[(size_t)gr * 512 + c] = acc[fi][fj][r] + a;
            }
        }
}

// standalone symmetric gram (small path), LPT-ordered grid 1088
__global__ __launch_bounds__(256) void gram_sym(const ushort_t* __restrict__ Ap,
                                                const float* __restrict__ sqb,
                                                float* __restrict__ D) {
    __shared__ __align__(16) ushort_t As[128 * 32];
    __shared__ __align__(16) ushort_t Bs[128 * 32];
    __shared__ __align__(16) float stg[4][1280];
    int blk = blockIdx.x;
    int z = blk & 7;
    int p = (blk < 960) ? (blk >> 3) : (120 + ((blk - 960) >> 3));
    int bi, bj;
    pair_decode(p, &bi, &bj);
    gram_body(As, Bs, stg[threadIdx.x >> 6],
              Ap + (size_t)z * N_ * KPC_, sqb + (size_t)z * N_,
              D + (size_t)z * N_ * N_, bi, bj);
}

// fused gram + uv gemm (big path): blocks [0,960) off-diag gram,
// [960,1472) uv gemm (tail-filler), [1472,1600) diag gram (cheap, last).
__global__ __launch_bounds__(256) void gram_uv(const ushort_t* __restrict__ Ap,
                                               const float* __restrict__ sqb,
                                               float* __restrict__ D,
                                               const ushort_t* __restrict__ Qcat,
                                               const float* __restrict__ bcat,
                                               float* __restrict__ uv) {
    __shared__ __align__(16) ushort_t As[128 * 32];
    __shared__ __align__(16) ushort_t Bs[128 * 32];
    __shared__ __align__(16) float stg[4][1280];
    int blk = blockIdx.x;
    if (blk >= 960 && blk < 1472) {
        uvgemm_body(As, Bs, Ap, Qcat, bcat, uv, blk - 960);
        return;
    }
    int z = blk & 7;
    int p = (blk < 960) ? (blk >> 3) : (120 + ((blk - 1472) >> 3));
    int bi, bj;
    pair_decode(p, &bi, &bj);
    gram_body(As, Bs, stg[threadIdx.x >> 6],
              Ap + (size_t)z * N_ * KPC_, sqb + (size_t)z * N_,
              D + (size_t)z * N_ * N_, bi, bj);
}

// ---- threshold top-16 smallest per row (exact, lex (value,col) tie-break) ----
// Cacheable reads: D is LLC-resident (written cacheable by gram one step ago).
__global__ __launch_bounds__(256) void topk16(const float* __restrict__ D,
                                              int* __restrict__ idxb) {
    __shared__ unsigned long long cand[4][256];
    __shared__ int cnt[4];
    int w = threadIdx.x >> 6, lane = threadIdx.x & 63;
    int row = blockIdx.x * 4 + w;
    const float* dp = D + (size_t)row * N_;
    unsigned sk[32];
#pragma unroll
    for (int t = 0; t < 8; ++t) {
        f32x4 v4 = *(const f32x4*)(dp + t * 256 + lane * 4);
#pragma unroll
        for (int j = 0; j < 4; ++j) {
            unsigned u = __float_as_uint(v4[j]);
            sk[t * 4 + j] = (u & 0x80000000u) ? ~u : (u | 0x80000000u);
        }
    }
    if (lane == 0) cnt[w] = 0;
    unsigned vm = sk[0];
#pragma unroll
    for (int i = 1; i < 32; ++i) vm = min(vm, sk[i]);
#pragma unroll
    for (int k = 2; k <= 64; k <<= 1) {
#pragma unroll
        for (int j = k >> 1; j > 0; j >>= 1) {
            unsigned pv = __shfl_xor(vm, j);
            bool up = ((lane & k) == 0);
            bool lower = ((lane & j) == 0);
            unsigned mn = min(vm, pv), mx = max(vm, pv);
            vm = (lower == up) ? mn : mx;
        }
    }
    unsigned T = __shfl(vm, 15);   // 16th smallest lane-min >= 16th order statistic
    __syncthreads();
#pragma unroll
    for (int i = 0; i < 32; ++i) {
        if (sk[i] <= T) {
            unsigned col = (unsigned)((i >> 2) * 256 + lane * 4 + (i & 3));
            int s = atomicAdd(&cnt[w], 1);
            if (s < 256) cand[w][s] = ((unsigned long long)sk[i] << 32) | col;
        }
    }
    __syncthreads();
    int cn = cnt[w];
    if (cn <= 64) {
        unsigned long long mykey = (lane < cn) ? cand[w][lane] : ~0ull;
        for (int it = 0; it < 16; ++it) {
            unsigned long long best = mykey;
#pragma unroll
            for (int off = 32; off; off >>= 1) {
                unsigned long long o = __shfl_xor(best, off);
                if (o < best) best = o;
            }
            if (mykey == best) mykey = ~0ull;
            if (lane == 0) idxb[row * 16 + it] = (int)(unsigned)(best & 0xffffffffu);
        }
    } else if (cn <= 256) {
        for (int it = 0; it < 16; ++it) {
            unsigned long long best = ~0ull;
            for (int i = lane; i < cn; i += 64) {
                unsigned long long c = cand[w][i];
                if (c < best) best = c;
            }
#pragma unroll
            for (int off = 32; off; off >>= 1) {
                unsigned long long o = __shfl_xor(best, off);
                if (o < best) best = o;
            }
            for (int i = lane; i < cn; i += 64)
                if (cand[w][i] == best) cand[w][i] = ~0ull;
            if (lane == 0) idxb[row * 16 + it] = (int)(unsigned)(best & 0xffffffffu);
        }
    } else {
        unsigned mask = 0;
        for (int it = 0; it < 16; ++it) {
            unsigned long long key = ~0ull;
#pragma unroll
            for (int i = 0; i < 32; ++i) {
                if (!((mask >> i) & 1u)) {
                    unsigned long long k2 = ((unsigned long long)sk[i] << 32) |
                        (unsigned)((i >> 2) * 256 + lane * 4 + (i & 3));
                    if (k2 < key) key = k2;
                }
            }
#pragma unroll
            for (int off = 32; off; off >>= 1) {
                unsigned long long o = __shfl_xor(key, off);
                if (o < key) key = o;
            }
            unsigned jc = (unsigned)(key & 0xffffffffu);
            int li = ((jc & 255) >> 2);
            int ii = ((jc >> 8) << 2) | (jc & 3);
            if (lane == li) mask |= 1u << ii;
            if (lane == 0) idxb[row * 16 + it] = (int)jc;
        }
    }
}

// t[b,i,h] = uv[row][h] + max_k uv[(b,idx_k)][256+h]; accumulates BN stats of t.
__global__ void gather_max(const float* __restrict__ uv, const int* __restrict__ idxb,
                           float* __restrict__ outp, double* __restrict__ stats) {
    int blk = blockIdx.x;
    int b = blk & 7;
    int strip = blk >> 3;               // 0..63
    int r0 = b * N_ + strip * 32;
    int f = threadIdx.x;
    float s1 = 0.f, s2 = 0.f;
    for (int rr = 0; rr < 32; ++rr) {
        int row = r0 + rr;
        const int* ip = idxb + row * 16;
        float m = -FLT_MAX;
#pragma unroll
        for (int k = 0; k < 16; ++k) {
            int j = ip[k];
            m = fmaxf(m, uv[((size_t)((b << 11) + j)) * 512 + 256 + f]);
        }
        float v = uv[(size_t)row * 512 + f] + m;
        outp[(size_t)row * H_ + f] = v;
        s1 += v; s2 += v * v;
    }
    atomicAdd(&stats[f], (double)s1);
    atomicAdd(&stats[H_ + f], (double)s2);
}

// BN+ReLU fused with compact split-bf16 packing and optional row sqnorm reduce.
// scale/shift computed in-block from the stats slot (bitwise-identical).
__global__ void bn_apply_pack(const float* __restrict__ X, const double* __restrict__ sums,
                              const float* __restrict__ g, const float* __restrict__ b,
                              ushort_t* __restrict__ Ap, float* __restrict__ sq) {
    __shared__ float scsh[512];
    int tid = threadIdx.x;
    {
        double m  = sums[tid] / (double)BN_;
        double var = sums[H_ + tid] / (double)BN_ - m * m;
        double inv = 1.0 / sqrt(var + 1e-5);
        float sc = g[tid] * (float)inv;
        scsh[tid] = sc;
        scsh[H_ + tid] = b[tid] - (float)m * sc;
    }
    __syncthreads();
    int row = blockIdx.x * 8 + (tid >> 5);
    int f0  = (tid & 31) * 8;
    const float* xp = X + (size_t)row * H_ + f0;
    f32x4 x0 = *(const f32x4*)(xp);
    f32x4 x1 = *(const f32x4*)(xp + 4);
    f32x4 sc0 = *(const f32x4*)(scsh + f0);
    f32x4 sc1 = *(const f32x4*)(scsh + f0 + 4);
    f32x4 sh0 = *(const f32x4*)(scsh + H_ + f0);
    f32x4 sh1 = *(const f32x4*)(scsh + H_ + f0 + 4);
    float v[8];
#pragma unroll
    for (int i = 0; i < 4; ++i) {
        v[i]     = fmaxf(x0[i] * sc0[i] + sh0[i], 0.f);
        v[i + 4] = fmaxf(x1[i] * sc1[i] + sh1[i], 0.f);
    }
    short8 hi8, lo8;
#pragma unroll
    for (int i = 0; i < 8; ++i) {
        ushort_t hi = f2bf(v[i]);
        ushort_t lo = f2bf(v[i] - bf2f(hi));
        hi8[i] = (short)hi; lo8[i] = (short)lo;
    }
    ushort_t* ap = Ap + (size_t)row * KPC_ + f0;
    *(short8*)(ap)      = hi8;
    *(short8*)(ap + H_) = lo8;
    if (sq) {
        float s = 0.f;
#pragma unroll
        for (int i = 0; i < 8; ++i) s += v[i] * v[i];
#pragma unroll
        for (int off = 16; off; off >>= 1) s += __shfl_down(s, off, 32);
        if ((tid & 31) == 0) sq[row] = s;
    }
}

// head gemm (N=512) with fused n-chunk maxpool: never materializes y.
__global__ __launch_bounds__(256) void head_gemm_pool(
    const ushort_t* __restrict__ P, const ushort_t* __restrict__ Q,
    const float* __restrict__ aux, float* __restrict__ pmax) {
    __shared__ __align__(16) ushort_t As[128 * 32];
    __shared__ __align__(16) ushort_t Bs[128 * 32];
    __shared__ float smax[2][2][64];
    int blk = blockIdx.x;
    int z = blk & 7;
    int rest = blk >> 3;
    int xb = rest & 3;
    int ys = rest >> 2;
    int i0 = (z * 16 + ys) * 128;
    int j0 = xb * 128;
    int tid = threadIdx.x;
    int lane = tid & 63, wave = tid >> 6;
    int wm = wave & 1, wn = wave >> 1;
    int m16 = lane & 15, kq = (lane >> 4) * 8;

    f32x4 acc[4][4];
    f32x4 zero = {0.f, 0.f, 0.f, 0.f};
#pragma unroll
    for (int i = 0; i < 4; ++i)
#pragma unroll
        for (int j = 0; j < 4; ++j) acc[i][j] = zero;

    int srow = tid >> 2;
    int skc  = (tid & 3) * 8;

    for (int k0 = 0; k0 < KP_; k0 += 32) {
        int ka = kmapA(k0), kb = kmapB(k0);
#pragma unroll
        for (int s = 0; s < 2; ++s) {
            int row = srow + s * 64;
            const ushort_t* gpA = P + (size_t)(i0 + row) * KPC_ + ka + skc;
            const ushort_t* gpB = Q + (size_t)(j0 + row) * KPC_ + kb + skc;
            __builtin_amdgcn_global_load_lds(
                (const __attribute__((address_space(1))) void*)gpA,
                (__attribute__((address_space(3))) void*)(As + (size_t)(wave * 64 + s * 256) * 8),
                16, 0, 0);
            __builtin_amdgcn_global_load_lds(
                (const __attribute__((address_space(1))) void*)gpB,
                (__attribute__((address_space(3))) void*)(Bs + (size_t)(wave * 64 + s * 256) * 8),
                16, 0, 0);
        }
        __syncthreads();
        short8 af[4], bfr[4];
#pragma unroll
        for (int fi = 0; fi < 4; ++fi)
            af[fi] = *(const short8*)(As + (wm * 64 + fi * 16 + m16) * 32 + kq);
#pragma unroll
        for (int fj = 0; fj < 4; ++fj)
            bfr[fj] = *(const short8*)(Bs + (wn * 64 + fj * 16 + m16) * 32 + kq);
#pragma unroll
        for (int fi = 0; fi < 4; ++fi)
#pragma unroll
            for (int fj = 0; fj < 4; ++fj)
                acc[fi][fj] = __builtin_amdgcn_mfma_f32_16x16x32_bf16(
                    af[fi], bfr[fj], acc[fi][fj], 0, 0, 0);
        __syncthreads();
    }
    float vmax[4];
#pragma unroll
    for (int fj = 0; fj < 4; ++fj) {
        int c = j0 + wn * 64 + m16 + fj * 16;
        float a = aux[c];
        float m = -FLT_MAX;
#pragma unroll
        for (int fi = 0; fi < 4; ++fi)
#pragma unroll
            for (int r = 0; r < 4; ++r)
                m = fmaxf(m, acc[fi][fj][r] + a);
        m = fmaxf(m, __shfl_xor(m, 16));
        m = fmaxf(m, __shfl_xor(m, 32));
        vmax[fj] = m;
    }
    if (lane < 16) {
#pragma unroll
        for (int fj = 0; fj < 4; ++fj)
            smax[wm][wn][fj * 16 + m16] = vmax[fj];
    }
    __syncthreads();
    if (tid < 128) {
        int wn2 = tid >> 6, off = tid & 63;
        float m = fmaxf(smax[0][wn2][off], smax[1][wn2][off]);
        pmax[((size_t)(z * 16 + ys)) * G_ + j0 + wn2 * 64 + off] = m;
    }
}

// fused head: 16-chunk maxpool + 3-layer MLP (replicates the proven 4-way
// K-split and red[0..3]+bias summation order -> bitwise-identical).
__global__ __launch_bounds__(256) void head3(const float* __restrict__ pmax,
    const float* __restrict__ Wm1, const float* __restrict__ bm1,
    const float* __restrict__ Wm2, const float* __restrict__ bm2,
    const float* __restrict__ Wm3, const float* __restrict__ bm3,
    float* __restrict__ out) {
    __shared__ float s0[512];
    __shared__ float s1[256];
    __shared__ float red[4][64];
    int b = blockIdx.x, tid = threadIdx.x;
    {
        float m0 = -FLT_MAX, m1 = -FLT_MAX;
        for (int c2 = 0; c2 < 16; ++c2) {
            m0 = fmaxf(m0, pmax[((size_t)(b * 16 + c2)) * G_ + tid]);
            m1 = fmaxf(m1, pmax[((size_t)(b * 16 + c2)) * G_ + 256 + tid]);
        }
        s0[tid] = m0; s0[256 + tid] = m1;
    }
    int cl = tid & 63, ks = tid >> 6;
    __syncthreads();
    // stage 1: 256 outs, K=512 (kper=128)
    for (int cg = 0; cg < 4; ++cg) {
        int c = cg * 64 + cl;
        const float* Apt = s0 + ks * 128;
        const float* Wp  = Wm1 + (size_t)(ks * 128) * M0_ + c;
        float acc = 0.f;
        for (int k = 0; k < 128; k += 8)
#pragma unroll
            for (int u2 = 0; u2 < 8; ++u2)
                acc += Apt[k + u2] * Wp[(size_t)(k + u2) * M0_];
        red[ks][cl] = acc;
        __syncthreads();
        if (ks == 0) {
            float s = red[0][cl] + red[1][cl] + red[2][cl] + red[3][cl] + bm1[c];
            s1[c] = fmaxf(s, 0.f);
        }
        __syncthreads();
    }
    // stage 2: 128 outs, K=256 (kper=64)
    float s2v[2];
    for (int cg = 0; cg < 2; ++cg) {
        int c = cg * 64 + cl;
        const float* Apt = s1 + ks * 64;
        const float* Wp  = Wm2 + (size_t)(ks * 64) * M1_ + c;
        float acc = 0.f;
        for (int k = 0; k < 64; k += 8)
#pragma unroll
            for (int u2 = 0; u2 < 8; ++u2)
                acc += Apt[k + u2] * Wp[(size_t)(k + u2) * M1_];
        red[ks][cl] = acc;
        __syncthreads();
        s2v[cg] = 0.f;
        if (ks == 0) {
            float s = red[0][cl] + red[1][cl] + red[2][cl] + red[3][cl] + bm2[c];
            s2v[cg] = fmaxf(s, 0.f);
        }
        __syncthreads();
    }
    if (ks == 0) { s0[cl] = s2v[0]; s0[64 + cl] = s2v[1]; }
    __syncthreads();
    // stage 3: 128 outs, K=128 (kper=32)
    for (int cg = 0; cg < 2; ++cg) {
        int c = cg * 64 + cl;
        const float* Apt = s0 + ks * 32;
        const float* Wp  = Wm3 + (size_t)(ks * 32) * C_ + c;
        float acc = 0.f;
        for (int k = 0; k < 32; k += 8)
#pragma unroll
            for (int u2 = 0; u2 < 8; ++u2)
                acc += Apt[k + u2] * Wp[(size_t)(k + u2) * C_];
        red[ks][cl] = acc;
        __syncthreads();
        if (ks == 0)
            out[(size_t)b * C_ + c] =
                red[0][cl] + red[1][cl] + red[2][cl] + red[3][cl] + bm3[c];
        __syncthreads();
    }
}

// ---------------- launch ----------------
extern "C" void kernel_launch(void* const* d_in, const int* in_sizes, int n_in,
                              void* d_out, int out_size, void* d_ws, size_t ws_size,
                              hipStream_t stream) {
    (void)in_sizes; (void)n_in; (void)out_size;
    if (ws_size < WS_SMALL) return;
    const bool big = (ws_size >= WS_BIG);

    const float* x    = (const float*)d_in[0];
    const float* Wf   = (const float*)d_in[2];
    const float* bfv  = (const float*)d_in[3];
    const float* Wnn  = (const float*)d_in[4];
    const float* bnn  = (const float*)d_in[5];
    const float* g1   = (const float*)d_in[6];
    const float* b1   = (const float*)d_in[7];
    const float* We   = (const float*)d_in[8];
    const float* be   = (const float*)d_in[9];
    const float* g2   = (const float*)d_in[10];
    const float* b2   = (const float*)d_in[11];
    const float* Wl   = (const float*)d_in[12];
    const float* bl   = (const float*)d_in[13];
    const float* alpha= (const float*)d_in[14];
    const float* gg   = (const float*)d_in[15];
    const float* bgb  = (const float*)d_in[16];
    const float* Wg   = (const float*)d_in[17];
    const float* bg2  = (const float*)d_in[18];
    const float* Wm1  = (const float*)d_in[19];
    const float* bm1  = (const float*)d_in[20];
    const float* Wm2  = (const float*)d_in[21];
    const float* bm2  = (const float*)d_in[22];
    const float* Wm3  = (const float*)d_in[23];
    const float* bm3  = (const float*)d_in[24];
    float* outp = (float*)d_out;

    char* ws = (char*)d_ws;
    float*    h    = (float*)(ws + OFF_H);
    ushort_t* Ap   = (ushort_t*)(ws + OFF_APACK);
    ushort_t* Qpk  = (ushort_t*)(ws + OFF_WPK);
    float*    bcatA= (float*)(ws + OFF_BCA);
    double*   sta  = (double*)(ws + OFF_STA);
    float*    sqb  = (float*)(ws + OFF_SQ);
    int*      idxb = (int*)  (ws + OFF_IDX);

    size_t offD = big ? OFF_DBIG : OFF_DSML;
    float*    dmat = (float*)(ws + offD);
    float*    t    = (float*)(ws + offD);                      // overlays D (dead)
    float*    uv   = big ? (float*)(ws + OFF_UVBIG)
                         : (float*)(ws + offD + (size_t)50331648);
    float*    pmax = (float*)(ws + offD + (size_t)84672512);   // overlays D (dead)

    ushort_t* Qwnn = Qpk + (size_t)WPK_WNN * KPC_;
    ushort_t* Qwg  = Qpk + (size_t)WPK_WG  * KPC_;

    // fused prep: feat+pack | weight packs | stats zero
    hipLaunchKernelGGL(prep, dim3(BN_ + 3840 + 9), dim3(256), 0, stream,
                       x, Wf, bfv, h, Ap, Wnn, Wl, Wg, We, be, Qpk, bcatA, sta);

    // t = h@Wnn+bnn via MFMA (t-stats -> slot 0), XCD-pinned
    hipLaunchKernelGGL(mfma_gemm, dim3(256), dim3(256), 0, stream,
                       Ap, Qwnn, bnn, t, H_, 0,
                       (const float*)nullptr, (const float*)nullptr, 0, sta, 2);

    for (int l = 0; l < L_; ++l) {
        const float* src1 = (l == 0) ? t : h;
        hipLaunchKernelGGL(bn_apply_pack, dim3(BN_ / 8), dim3(256), 0, stream,
                           src1, sta + (size_t)(2 * l) * 512,
                           g1 + l * H_, b1 + l * H_, Ap, sqb);
        if (big) {
            // fused: gram (off-diag first, diag last) + uv gemm tail-filler
            hipLaunchKernelGGL(gram_uv, dim3(1600), dim3(256), 0, stream,
                               Ap, sqb, dmat,
                               Qpk + (size_t)(WPK_QCAT + l * 512) * KPC_,
                               bcatA + (size_t)l * 512, uv);
            hipLaunchKernelGGL(topk16, dim3(BN_ / 4), dim3(256), 0, stream, dmat, idxb);
        } else {
            hipLaunchKernelGGL(gram_sym, dim3(1088), dim3(256), 0, stream,
                               Ap, sqb, dmat);
            hipLaunchKernelGGL(topk16, dim3(BN_ / 4), dim3(256), 0, stream, dmat, idxb);
            hipLaunchKernelGGL(mfma_gemm, dim3(512), dim3(256), 0, stream,
                               Ap, Qpk + (size_t)(WPK_QCAT + l * 512) * KPC_,
                               bcatA + (size_t)l * 512, uv, 512, 0,
                               (const float*)nullptr, (const float*)nullptr, 0,
                               (double*)nullptr, 4);
        }
        hipLaunchKernelGGL(gather_max, dim3(512), dim3(256), 0, stream,
                           uv, idxb, t, sta + (size_t)(2 * l + 1) * 512);
        hipLaunchKernelGGL(bn_apply_pack, dim3(BN_ / 8), dim3(256), 0, stream,
                           t, sta + (size_t)(2 * l + 1) * 512,
                           g2 + l * H_, b2 + l * H_, Ap, (float*)nullptr);
        hipLaunchKernelGGL(mfma_gemm, dim3(256), dim3(256), 0, stream,
                           Ap, Qpk + (size_t)(WPK_WL + l * 256) * KPC_,
                           bl + (size_t)l * H_, h, H_, 2,
                           h, alpha, l, sta + (size_t)(2 * l + 2) * 512, 2);
    }

    // head: BN from slot 8, pack, fused Wg-gemm+pool, fused pool2+MLP
    hipLaunchKernelGGL(bn_apply_pack, dim3(BN_ / 8), dim3(256), 0, stream,
                       h, sta + (size_t)8 * 512, gg, bgb, Ap, (float*)nullptr);
    hipLaunchKernelGGL(head_gemm_pool, dim3(512), dim3(256), 0, stream,
                       Ap, Qwg, bg2, pmax);
    hipLaunchKernelGGL(head3, dim3(8), dim3(256), 0, stream,
                       pmax, Wm1, bm1, Wm2, bm2, Wm3, bm3, outp);
}